// Round 1
// baseline (730.189 us; speedup 1.0000x reference)
//
#include <hip/hip_runtime.h>
#include <hip/hip_bf16.h>

#define DIM 1024
#define HEADS 16
#define BATCH 2
#define SEQ 2048
#define MROWS (BATCH*SEQ)   // 4096

typedef __bf16 bf16_t;
typedef __bf16 bf16x8 __attribute__((ext_vector_type(8)));
typedef __bf16 bf16x4 __attribute__((ext_vector_type(4)));
typedef float  f32x4  __attribute__((ext_vector_type(4)));

// ---------------- small f32 helpers for the power iteration ----------------

__device__ inline float waveReduceSum(float v) {
#pragma unroll
    for (int off = 32; off > 0; off >>= 1) v += __shfl_down(v, off, 64);
    return v;  // lane 0 of each wave holds the wave sum
}

// y[row] = dot(W[row, :], x)   (one block per row)
__global__ __launch_bounds__(256) void matvec_rows(const float* __restrict__ W,
                                                   const float* __restrict__ x,
                                                   float* __restrict__ y, int C) {
    const int row = blockIdx.x;
    const float* Wr = W + (size_t)row * C;
    float acc = 0.f;
    for (int j = threadIdx.x; j < C; j += 256) acc += Wr[j] * x[j];
    __shared__ float red[4];
    float s = waveReduceSum(acc);
    if ((threadIdx.x & 63) == 0) red[threadIdx.x >> 6] = s;
    __syncthreads();
    if (threadIdx.x == 0) y[row] = red[0] + red[1] + red[2] + red[3];
}

// out[j] = dot(W[:, j], v)   (256 columns per block, coalesced)
__global__ __launch_bounds__(256) void matvec_cols(const float* __restrict__ W,
                                                   const float* __restrict__ v,
                                                   float* __restrict__ out, int R, int C) {
    const int j = blockIdx.x * 256 + threadIdx.x;
    float acc = 0.f;
    for (int i = 0; i < R; ++i) acc += W[(size_t)i * C + j] * v[i];
    out[j] = acc;
}

// v /= ||v||  (single block)
__global__ __launch_bounds__(256) void normalize_vec(float* __restrict__ v, int L) {
    float acc = 0.f;
    for (int i = threadIdx.x; i < L; i += 256) { float t = v[i]; acc += t * t; }
    __shared__ float red[4];
    __shared__ float invn;
    float s = waveReduceSum(acc);
    if ((threadIdx.x & 63) == 0) red[threadIdx.x >> 6] = s;
    __syncthreads();
    if (threadIdx.x == 0) invn = rsqrtf(red[0] + red[1] + red[2] + red[3]);
    __syncthreads();
    const float iv = invn;
    for (int i = threadIdx.x; i < L; i += 256) v[i] *= iv;
}

// scale[0] = sp[0] / dot(v, t)   (single block)
__global__ __launch_bounds__(256) void finalize_scale(const float* __restrict__ v,
                                                      const float* __restrict__ t,
                                                      const float* __restrict__ sp,
                                                      float* __restrict__ scale, int L) {
    float acc = 0.f;
    for (int i = threadIdx.x; i < L; i += 256) acc += v[i] * t[i];
    __shared__ float red[4];
    float s = waveReduceSum(acc);
    if ((threadIdx.x & 63) == 0) red[threadIdx.x >> 6] = s;
    __syncthreads();
    if (threadIdx.x == 0) scale[0] = sp[0] / (red[0] + red[1] + red[2] + red[3]);
}

// ---------------- conversions ----------------

__global__ __launch_bounds__(256) void convert_x(const float* __restrict__ X,
                                                 bf16_t* __restrict__ Xb, int n) {
    int i = (blockIdx.x * 256 + threadIdx.x) * 4;
    if (i + 3 < n) {
        float4 v = *(const float4*)(X + i);
        bf16x4 o;
        o[0] = (bf16_t)v.x; o[1] = (bf16_t)v.y; o[2] = (bf16_t)v.z; o[3] = (bf16_t)v.w;
        *(bf16x4*)(Xb + i) = o;
    }
}

// Wt[c][r] = bf16(W[r][c] * scale)   — 32x32 LDS-tiled transpose
__global__ __launch_bounds__(256) void convert_wt(const float* __restrict__ W,
                                                  bf16_t* __restrict__ Wt,
                                                  const float* __restrict__ scalep,
                                                  int R, int C) {
    __shared__ float t[32][33];
    const float s = *scalep;
    const int bx = blockIdx.x * 32;  // col block (C dim)
    const int by = blockIdx.y * 32;  // row block (R dim)
    const int tx = threadIdx.x & 31;
    const int ty = threadIdx.x >> 5;  // 0..7
#pragma unroll
    for (int j = ty; j < 32; j += 8)
        t[j][tx] = W[(size_t)(by + j) * C + bx + tx];
    __syncthreads();
#pragma unroll
    for (int j = ty; j < 32; j += 8)
        Wt[(size_t)(bx + j) * R + by + tx] = (bf16_t)(t[tx][j] * s);
}

// ---------------- bf16 MFMA GEMM: C[M][N] = A[M][K] * Bt[N][K]^T ----------------
// 128x128 tile, BK=32, 4 waves (2x2 of 64x64), 16x16x32 MFMA.

template <int OUT_BF16>
__global__ __launch_bounds__(256) void gemm_bf16_128(const bf16_t* __restrict__ A,
                                                     const bf16_t* __restrict__ Bt,
                                                     bf16_t* __restrict__ Cb,
                                                     float* __restrict__ Cf,
                                                     int M, int N, int K) {
    __shared__ __align__(16) bf16_t tA[128][40];
    __shared__ __align__(16) bf16_t tB[128][40];
    const int tid = threadIdx.x;
    const int wave = tid >> 6, lane = tid & 63, lhi = lane >> 4, llo = lane & 15;
    const int wr = wave >> 1, wc = wave & 1;
    const int rowBase = blockIdx.y * 128, colBase = blockIdx.x * 128;
    f32x4 acc[4][4] = {};
    const int rs = tid >> 2, c8 = (tid & 3) * 8;
    for (int k0 = 0; k0 < K; k0 += 32) {
        __syncthreads();
#pragma unroll
        for (int it = 0; it < 2; ++it) {
            const int r = it * 64 + rs;
            *(bf16x8*)&tA[r][c8] = *(const bf16x8*)&A[(size_t)(rowBase + r) * K + k0 + c8];
            *(bf16x8*)&tB[r][c8] = *(const bf16x8*)&Bt[(size_t)(colBase + r) * K + k0 + c8];
        }
        __syncthreads();
        bf16x8 af[4], bfr[4];
#pragma unroll
        for (int m = 0; m < 4; ++m) af[m] = *(const bf16x8*)&tA[wr * 64 + m * 16 + llo][lhi * 8];
#pragma unroll
        for (int n = 0; n < 4; ++n) bfr[n] = *(const bf16x8*)&tB[wc * 64 + n * 16 + llo][lhi * 8];
#pragma unroll
        for (int m = 0; m < 4; ++m)
#pragma unroll
            for (int n = 0; n < 4; ++n)
                acc[m][n] = __builtin_amdgcn_mfma_f32_16x16x32_bf16(af[m], bfr[n], acc[m][n], 0, 0, 0);
    }
#pragma unroll
    for (int m = 0; m < 4; ++m) {
        const int row0 = rowBase + wr * 64 + m * 16 + lhi * 4;
#pragma unroll
        for (int n = 0; n < 4; ++n) {
            const int col = colBase + wc * 64 + n * 16 + llo;
#pragma unroll
            for (int r2 = 0; r2 < 4; ++r2) {
                const size_t idx = (size_t)(row0 + r2) * N + col;
                if (OUT_BF16) Cb[idx] = (bf16_t)acc[m][n][r2];
                else          Cf[idx] = acc[m][n][r2];
            }
        }
    }
}

// ---------------- causal flash attention, bf16 MFMA ----------------
// grid: (SEQ/64, BATCH*HEADS), block 256 (4 waves x 16 q-rows).

__global__ __launch_bounds__(256) void flash_attn(const bf16_t* __restrict__ QKV,
                                                  bf16_t* __restrict__ Oout) {
    const int qb = blockIdx.x;
    const int bh = blockIdx.y;
    const int b = bh >> 4, h = bh & 15;
    const int tid = threadIdx.x;
    const int wave = tid >> 6, lane = tid & 63, lhi = lane >> 4, llo = lane & 15;
    const size_t rstride = 3 * DIM;
    const bf16_t* Qb = QKV + (size_t)b * SEQ * rstride + h * 64;
    const bf16_t* Kb = Qb + DIM;
    const bf16_t* Vb = Qb + 2 * DIM;

    __shared__ __align__(16) bf16_t Kt[64][72];
    __shared__ __align__(16) bf16_t Vt[64][72];   // transposed V: [d][key]
    __shared__ __align__(16) bf16_t Pt[4][16][72];

    // Q fragments (stay in registers the whole kernel)
    const int qrow = qb * 64 + wave * 16 + llo;
    const bf16_t* qp = Qb + (size_t)qrow * rstride + lhi * 8;
    bf16x8 qf[2];
    qf[0] = *(const bf16x8*)qp;
    qf[1] = *(const bf16x8*)(qp + 32);

    f32x4 oacc[4] = {};
    float mrun[4] = {-1e30f, -1e30f, -1e30f, -1e30f};
    float lrun[4] = {0.f, 0.f, 0.f, 0.f};
    const float scl = 0.125f;  // hd^-0.5

    for (int kt = 0; kt <= qb; ++kt) {
        __syncthreads();
        // stage K tile and transposed V tile
#pragma unroll
        for (int it = 0; it < 2; ++it) {
            const int chunk = tid + it * 256;
            const int row = chunk >> 3, c8 = (chunk & 7) * 8;
            bf16x8 kv = *(const bf16x8*)&Kb[(size_t)(kt * 64 + row) * rstride + c8];
            *(bf16x8*)&Kt[row][c8] = kv;
            bf16x8 vv = *(const bf16x8*)&Vb[(size_t)(kt * 64 + row) * rstride + c8];
#pragma unroll
            for (int j = 0; j < 8; ++j) Vt[c8 + j][row] = vv[j];
        }
        __syncthreads();

        // S = Q K^T  (16q x 64k per wave)
        f32x4 s[4] = {};
#pragma unroll
        for (int nb = 0; nb < 4; ++nb) {
#pragma unroll
            for (int st = 0; st < 2; ++st) {
                bf16x8 kf = *(const bf16x8*)&Kt[nb * 16 + llo][st * 32 + lhi * 8];
                s[nb] = __builtin_amdgcn_mfma_f32_16x16x32_bf16(qf[st], kf, s[nb], 0, 0, 0);
            }
        }

        // mask + scale
        float p[4][4];
        float mtile[4] = {-1e30f, -1e30f, -1e30f, -1e30f};
        const int q0 = qb * 64 + wave * 16 + lhi * 4;
        const int k0g = kt * 64 + llo;
#pragma unroll
        for (int nb = 0; nb < 4; ++nb)
#pragma unroll
            for (int r = 0; r < 4; ++r) {
                float sv = s[nb][r] * scl;
                if (k0g + nb * 16 > q0 + r) sv = -1e30f;
                p[nb][r] = sv;
                mtile[r] = fmaxf(mtile[r], sv);
            }
        // row max across the 16-lane column group
#pragma unroll
        for (int off = 1; off < 16; off <<= 1)
#pragma unroll
            for (int r = 0; r < 4; ++r) mtile[r] = fmaxf(mtile[r], __shfl_xor(mtile[r], off, 64));

        float alpha[4];
#pragma unroll
        for (int r = 0; r < 4; ++r) {
            float mnew = fmaxf(mrun[r], mtile[r]);
            alpha[r] = __expf(mrun[r] - mnew);
            mrun[r] = mnew;
        }
        float lt[4] = {0.f, 0.f, 0.f, 0.f};
#pragma unroll
        for (int nb = 0; nb < 4; ++nb)
#pragma unroll
            for (int r = 0; r < 4; ++r) {
                float e = __expf(p[nb][r] - mrun[r]);
                p[nb][r] = e;
                lt[r] += e;
            }
#pragma unroll
        for (int off = 1; off < 16; off <<= 1)
#pragma unroll
            for (int r = 0; r < 4; ++r) lt[r] += __shfl_xor(lt[r], off, 64);
#pragma unroll
        for (int r = 0; r < 4; ++r) lrun[r] = lrun[r] * alpha[r] + lt[r];
#pragma unroll
        for (int d = 0; d < 4; ++d)
#pragma unroll
            for (int r = 0; r < 4; ++r) oacc[d][r] *= alpha[r];

        // P -> per-wave LDS (re-layout for PV A-operand); wave-local dependency
#pragma unroll
        for (int nb = 0; nb < 4; ++nb)
#pragma unroll
            for (int r = 0; r < 4; ++r)
                Pt[wave][lhi * 4 + r][nb * 16 + llo] = (bf16_t)p[nb][r];

        // O += P V
#pragma unroll
        for (int st = 0; st < 2; ++st) {
            bf16x8 pf = *(const bf16x8*)&Pt[wave][llo][st * 32 + lhi * 8];
#pragma unroll
            for (int d = 0; d < 4; ++d) {
                bf16x8 vf = *(const bf16x8*)&Vt[d * 16 + llo][st * 32 + lhi * 8];
                oacc[d] = __builtin_amdgcn_mfma_f32_16x16x32_bf16(pf, vf, oacc[d], 0, 0, 0);
            }
        }
    }

    // epilogue: divide by l, store bf16
    const int q0 = qb * 64 + wave * 16 + lhi * 4;
#pragma unroll
    for (int r = 0; r < 4; ++r) {
        const float inv = 1.0f / lrun[r];
        const size_t orow = (size_t)(b * SEQ + q0 + r) * DIM + h * 64;
#pragma unroll
        for (int d = 0; d < 4; ++d)
            Oout[orow + d * 16 + llo] = (bf16_t)(oacc[d][r] * inv);
    }
}

// ---------------- launch ----------------

extern "C" void kernel_launch(void* const* d_in, const int* in_sizes, int n_in,
                              void* d_out, int out_size, void* d_ws, size_t ws_size,
                              hipStream_t stream) {
    (void)in_sizes; (void)n_in; (void)out_size; (void)ws_size;
    const float* batch   = (const float*)d_in[0];
    const float* W_qkv   = (const float*)d_in[1];
    const float* u_qkv   = (const float*)d_in[2];
    const float* sg_qkv  = (const float*)d_in[3];
    const float* W_proj  = (const float*)d_in[4];
    const float* u_proj  = (const float*)d_in[5];
    const float* sg_proj = (const float*)d_in[6];
    float* out = (float*)d_out;

    char* ws = (char*)d_ws;
    size_t off = 0;
    auto alloc = [&](size_t bytes) -> void* {
        void* p = ws + off;
        off = (off + bytes + 255) & ~(size_t)255;
        return p;
    };
    float* v_q  = (float*)alloc(1024 * 4);
    float* u2_q = (float*)alloc(3072 * 4);
    float* t_q  = (float*)alloc(1024 * 4);
    float* sc_q = (float*)alloc(4);
    float* v_p  = (float*)alloc(1024 * 4);
    float* u2_p = (float*)alloc(1024 * 4);
    float* t_p  = (float*)alloc(1024 * 4);
    float* sc_p = (float*)alloc(4);
    bf16_t* Xb   = (bf16_t*)alloc((size_t)MROWS * DIM * 2);
    bf16_t* Wtq  = (bf16_t*)alloc((size_t)3 * DIM * DIM * 2);
    bf16_t* Wtp  = (bf16_t*)alloc((size_t)DIM * DIM * 2);
    bf16_t* QKVb = (bf16_t*)alloc((size_t)MROWS * 3 * DIM * 2);
    bf16_t* AOb  = (bf16_t*)alloc((size_t)MROWS * DIM * 2);

    // sigma for W_qkv [1024 x 3072]
    matvec_rows<<<1024, 256, 0, stream>>>(W_qkv, u_qkv, v_q, 3072);
    normalize_vec<<<1, 256, 0, stream>>>(v_q, 1024);
    matvec_cols<<<12, 256, 0, stream>>>(W_qkv, v_q, u2_q, 1024, 3072);
    normalize_vec<<<1, 256, 0, stream>>>(u2_q, 3072);
    matvec_rows<<<1024, 256, 0, stream>>>(W_qkv, u2_q, t_q, 3072);
    finalize_scale<<<1, 256, 0, stream>>>(v_q, t_q, sg_qkv, sc_q, 1024);

    // sigma for W_proj [1024 x 1024]
    matvec_rows<<<1024, 256, 0, stream>>>(W_proj, u_proj, v_p, 1024);
    normalize_vec<<<1, 256, 0, stream>>>(v_p, 1024);
    matvec_cols<<<4, 256, 0, stream>>>(W_proj, v_p, u2_p, 1024, 1024);
    normalize_vec<<<1, 256, 0, stream>>>(u2_p, 1024);
    matvec_rows<<<1024, 256, 0, stream>>>(W_proj, u2_p, t_p, 1024);
    finalize_scale<<<1, 256, 0, stream>>>(v_p, t_p, sg_proj, sc_p, 1024);

    // conversions
    convert_x<<<(MROWS * DIM) / (256 * 4), 256, 0, stream>>>(batch, Xb, MROWS * DIM);
    convert_wt<<<dim3(3 * DIM / 32, DIM / 32), 256, 0, stream>>>(W_qkv, Wtq, sc_q, DIM, 3 * DIM);
    convert_wt<<<dim3(DIM / 32, DIM / 32), 256, 0, stream>>>(W_proj, Wtp, sc_p, DIM, DIM);

    // QKV = Xb @ (s*W_qkv)   [4096 x 3072]
    gemm_bf16_128<1><<<dim3(3 * DIM / 128, MROWS / 128), 256, 0, stream>>>(
        Xb, Wtq, QKVb, nullptr, MROWS, 3 * DIM, DIM);

    // attention
    flash_attn<<<dim3(SEQ / 64, BATCH * HEADS), 256, 0, stream>>>(QKVb, AOb);

    // out = AOb @ (s*W_proj)   [4096 x 1024], f32 out
    gemm_bf16_128<0><<<dim3(DIM / 128, MROWS / 128), 256, 0, stream>>>(
        AOb, Wtp, nullptr, out, MROWS, DIM, DIM);
}

// Round 2
// 281.191 us; speedup vs baseline: 2.5968x; 2.5968x over previous
//
#include <hip/hip_runtime.h>
#include <hip/hip_bf16.h>

#define DIM 1024
#define HEADS 16
#define BATCH 2
#define SEQ 2048
#define MROWS (BATCH*SEQ)   // 4096

typedef __bf16 bf16_t;
typedef __bf16 bf16x8 __attribute__((ext_vector_type(8)));
typedef __bf16 bf16x4 __attribute__((ext_vector_type(4)));
typedef float  f32x4  __attribute__((ext_vector_type(4)));

__device__ inline float waveReduceSum(float v) {
#pragma unroll
    for (int off = 32; off > 0; off >>= 1) v += __shfl_down(v, off, 64);
    return v;
}

// async global->LDS 16B (m97 pattern): LDS dest is wave-uniform base; HW writes
// base + lane*16. Global src is per-lane.
__device__ inline void gload_lds16(const bf16_t* g, bf16_t* l) {
    __builtin_amdgcn_global_load_lds(
        (const __attribute__((address_space(1))) void*)g,
        (__attribute__((address_space(3))) void*)l,
        16, 0, 0);
}

// ---------------- power iteration: scale = sp * ||W@u|| / ||W^T(W@u)|| --------

// y[row] = dot(W[row,:], x)  (one block per row)
__global__ __launch_bounds__(256) void matvec_rows(const float* __restrict__ W,
                                                   const float* __restrict__ x,
                                                   float* __restrict__ y, int C) {
    const int row = blockIdx.x;
    const float* Wr = W + (size_t)row * C;
    float acc = 0.f;
    for (int j = threadIdx.x; j < C; j += 256) acc += Wr[j] * x[j];
    __shared__ float red[4];
    float s = waveReduceSum(acc);
    if ((threadIdx.x & 63) == 0) red[threadIdx.x >> 6] = s;
    __syncthreads();
    if (threadIdx.x == 0) y[row] = red[0] + red[1] + red[2] + red[3];
}

// part[p][j] = sum_{i in chunk p} W[i,j]*y[i]   chunk=128 rows, grid (C/256, R/128)
__global__ __launch_bounds__(256) void matvec_cols_part(const float* __restrict__ W,
                                                        const float* __restrict__ y,
                                                        float* __restrict__ part, int C) {
    const int j = blockIdx.x * 256 + threadIdx.x;
    const int i0 = blockIdx.y * 128;
    float acc = 0.f;
#pragma unroll 4
    for (int i = i0; i < i0 + 128; ++i) acc += W[(size_t)i * C + j] * y[i];
    part[(size_t)blockIdx.y * C + j] = acc;
}

// scale = sp * ||y|| / ||z||, z[j] = sum_p part[p][j]  (single block, 1024 thr)
__global__ __launch_bounds__(1024) void norm_scale(const float* __restrict__ y, int R,
                                                   const float* __restrict__ part, int C,
                                                   const float* __restrict__ sp,
                                                   float* __restrict__ scale) {
    float accY = 0.f, accZ = 0.f;
    for (int i = threadIdx.x; i < R; i += 1024) { float t = y[i]; accY += t * t; }
    for (int j = threadIdx.x; j < C; j += 1024) {
        float z = 0.f;
#pragma unroll
        for (int p = 0; p < 8; ++p) z += part[(size_t)p * C + j];
        accZ += z * z;
    }
    __shared__ float redY[16], redZ[16];
    float sy = waveReduceSum(accY), sz = waveReduceSum(accZ);
    const int w = threadIdx.x >> 6;
    if ((threadIdx.x & 63) == 0) { redY[w] = sy; redZ[w] = sz; }
    __syncthreads();
    if (threadIdx.x == 0) {
        float SY = 0.f, SZ = 0.f;
#pragma unroll
        for (int i = 0; i < 16; ++i) { SY += redY[i]; SZ += redZ[i]; }
        scale[0] = sp[0] * sqrtf(SY) / sqrtf(SZ);
    }
}

// ---------------- conversions ----------------

__global__ __launch_bounds__(256) void convert_x(const float* __restrict__ X,
                                                 bf16_t* __restrict__ Xb, int n) {
    int i = (blockIdx.x * 256 + threadIdx.x) * 4;
    if (i + 3 < n) {
        float4 v = *(const float4*)(X + i);
        bf16x4 o;
        o[0] = (bf16_t)v.x; o[1] = (bf16_t)v.y; o[2] = (bf16_t)v.z; o[3] = (bf16_t)v.w;
        *(bf16x4*)(Xb + i) = o;
    }
}

// Wt[c][r] = bf16(W[r][c] * scale)   — 32x32 LDS-tiled transpose
__global__ __launch_bounds__(256) void convert_wt(const float* __restrict__ W,
                                                  bf16_t* __restrict__ Wt,
                                                  const float* __restrict__ scalep,
                                                  int R, int C) {
    __shared__ float t[32][33];
    const float s = *scalep;
    const int bx = blockIdx.x * 32;
    const int by = blockIdx.y * 32;
    const int tx = threadIdx.x & 31;
    const int ty = threadIdx.x >> 5;
#pragma unroll
    for (int j = ty; j < 32; j += 8)
        t[j][tx] = W[(size_t)(by + j) * C + bx + tx];
    __syncthreads();
#pragma unroll
    for (int j = ty; j < 32; j += 8)
        Wt[(size_t)(bx + j) * R + by + tx] = (bf16_t)(t[tx][j] * s);
}

// ---------------- bf16 MFMA GEMM (m97 structure): C = A[M][K] * Bt[N][K]^T ----
// 128x128 tile, BK=32, 4 waves (2x2 of 64x64), global_load_lds width-16 staging,
// linear LDS [128][32].

template <int OUT_BF16>
__global__ __launch_bounds__(256) void gemm_bf16_128(const bf16_t* __restrict__ A,
                                                     const bf16_t* __restrict__ Bt,
                                                     bf16_t* __restrict__ Cb,
                                                     float* __restrict__ Cf,
                                                     int M, int N, int K) {
    __shared__ __align__(16) bf16_t tA[128 * 32];
    __shared__ __align__(16) bf16_t tB[128 * 32];
    const int tid = threadIdx.x;
    const int wave = tid >> 6, lane = tid & 63, lhi = lane >> 4, llo = lane & 15;
    const int wr = wave >> 1, wc = wave & 1;
    const int rowBase = blockIdx.y * 128, colBase = blockIdx.x * 128;

    // staging: pass p, wave w, lane l -> LDS element w*512 + l*8 (+ p*2048)
    //          = row (p*64 + w*16 + l/4), col (l&3)*8 of [128][32]
    const int srow = wave * 16 + (lane >> 2);
    const int scol = (lane & 3) * 8;
    const bf16_t* pA0 = &A[(size_t)(rowBase + srow) * K + scol];
    const bf16_t* pA1 = &A[(size_t)(rowBase + 64 + srow) * K + scol];
    const bf16_t* pB0 = &Bt[(size_t)(colBase + srow) * K + scol];
    const bf16_t* pB1 = &Bt[(size_t)(colBase + 64 + srow) * K + scol];
    bf16_t* dA0 = tA + wave * 512;
    bf16_t* dA1 = tA + 2048 + wave * 512;
    bf16_t* dB0 = tB + wave * 512;
    bf16_t* dB1 = tB + 2048 + wave * 512;

    f32x4 acc[4][4] = {};
    for (int k0 = 0; k0 < K; k0 += 32) {
        __syncthreads();
        gload_lds16(pA0 + k0, dA0);
        gload_lds16(pA1 + k0, dA1);
        gload_lds16(pB0 + k0, dB0);
        gload_lds16(pB1 + k0, dB1);
        __syncthreads();
        bf16x8 af[4], bfr[4];
#pragma unroll
        for (int m = 0; m < 4; ++m)
            af[m] = *(const bf16x8*)&tA[(wr * 64 + m * 16 + llo) * 32 + lhi * 8];
#pragma unroll
        for (int n = 0; n < 4; ++n)
            bfr[n] = *(const bf16x8*)&tB[(wc * 64 + n * 16 + llo) * 32 + lhi * 8];
#pragma unroll
        for (int m = 0; m < 4; ++m)
#pragma unroll
            for (int n = 0; n < 4; ++n)
                acc[m][n] = __builtin_amdgcn_mfma_f32_16x16x32_bf16(af[m], bfr[n], acc[m][n], 0, 0, 0);
    }
#pragma unroll
    for (int m = 0; m < 4; ++m) {
        const int row0 = rowBase + wr * 64 + m * 16 + lhi * 4;
#pragma unroll
        for (int n = 0; n < 4; ++n) {
            const int col = colBase + wc * 64 + n * 16 + llo;
#pragma unroll
            for (int r2 = 0; r2 < 4; ++r2) {
                const size_t idx = (size_t)(row0 + r2) * N + col;
                if (OUT_BF16) Cb[idx] = (bf16_t)acc[m][n][r2];
                else          Cf[idx] = acc[m][n][r2];
            }
        }
    }
}

// ---------------- causal flash attention, bf16 MFMA ----------------

__global__ __launch_bounds__(256) void flash_attn(const bf16_t* __restrict__ QKV,
                                                  bf16_t* __restrict__ Oout) {
    const int qb = blockIdx.x;
    const int bh = blockIdx.y;
    const int b = bh >> 4, h = bh & 15;
    const int tid = threadIdx.x;
    const int wave = tid >> 6, lane = tid & 63, lhi = lane >> 4, llo = lane & 15;
    const size_t rstride = 3 * DIM;
    const bf16_t* Qb = QKV + (size_t)b * SEQ * rstride + h * 64;
    const bf16_t* Kb = Qb + DIM;
    const bf16_t* Vb = Qb + 2 * DIM;

    __shared__ __align__(16) bf16_t Kt[64][72];
    __shared__ __align__(16) bf16_t Vt[64][72];
    __shared__ __align__(16) bf16_t Pt[4][16][72];

    const int qrow = qb * 64 + wave * 16 + llo;
    const bf16_t* qp = Qb + (size_t)qrow * rstride + lhi * 8;
    bf16x8 qf[2];
    qf[0] = *(const bf16x8*)qp;
    qf[1] = *(const bf16x8*)(qp + 32);

    f32x4 oacc[4] = {};
    float mrun[4] = {-1e30f, -1e30f, -1e30f, -1e30f};
    float lrun[4] = {0.f, 0.f, 0.f, 0.f};
    const float scl = 0.125f;

    for (int kt = 0; kt <= qb; ++kt) {
        __syncthreads();
#pragma unroll
        for (int it = 0; it < 2; ++it) {
            const int chunk = tid + it * 256;
            const int row = chunk >> 3, c8 = (chunk & 7) * 8;
            bf16x8 kv = *(const bf16x8*)&Kb[(size_t)(kt * 64 + row) * rstride + c8];
            *(bf16x8*)&Kt[row][c8] = kv;
            bf16x8 vv = *(const bf16x8*)&Vb[(size_t)(kt * 64 + row) * rstride + c8];
#pragma unroll
            for (int j = 0; j < 8; ++j) Vt[c8 + j][row] = vv[j];
        }
        __syncthreads();

        f32x4 s[4] = {};
#pragma unroll
        for (int nb = 0; nb < 4; ++nb) {
#pragma unroll
            for (int st = 0; st < 2; ++st) {
                bf16x8 kf = *(const bf16x8*)&Kt[nb * 16 + llo][st * 32 + lhi * 8];
                s[nb] = __builtin_amdgcn_mfma_f32_16x16x32_bf16(qf[st], kf, s[nb], 0, 0, 0);
            }
        }

        float p[4][4];
        float mtile[4] = {-1e30f, -1e30f, -1e30f, -1e30f};
        const int q0 = qb * 64 + wave * 16 + lhi * 4;
        const int k0g = kt * 64 + llo;
#pragma unroll
        for (int nb = 0; nb < 4; ++nb)
#pragma unroll
            for (int r = 0; r < 4; ++r) {
                float sv = s[nb][r] * scl;
                if (k0g + nb * 16 > q0 + r) sv = -1e30f;
                p[nb][r] = sv;
                mtile[r] = fmaxf(mtile[r], sv);
            }
#pragma unroll
        for (int off = 1; off < 16; off <<= 1)
#pragma unroll
            for (int r = 0; r < 4; ++r) mtile[r] = fmaxf(mtile[r], __shfl_xor(mtile[r], off, 64));

        float alpha[4];
#pragma unroll
        for (int r = 0; r < 4; ++r) {
            float mnew = fmaxf(mrun[r], mtile[r]);
            alpha[r] = __expf(mrun[r] - mnew);
            mrun[r] = mnew;
        }
        float lt[4] = {0.f, 0.f, 0.f, 0.f};
#pragma unroll
        for (int nb = 0; nb < 4; ++nb)
#pragma unroll
            for (int r = 0; r < 4; ++r) {
                float e = __expf(p[nb][r] - mrun[r]);
                p[nb][r] = e;
                lt[r] += e;
            }
#pragma unroll
        for (int off = 1; off < 16; off <<= 1)
#pragma unroll
            for (int r = 0; r < 4; ++r) lt[r] += __shfl_xor(lt[r], off, 64);
#pragma unroll
        for (int r = 0; r < 4; ++r) lrun[r] = lrun[r] * alpha[r] + lt[r];
#pragma unroll
        for (int d = 0; d < 4; ++d)
#pragma unroll
            for (int r = 0; r < 4; ++r) oacc[d][r] *= alpha[r];

#pragma unroll
        for (int nb = 0; nb < 4; ++nb)
#pragma unroll
            for (int r = 0; r < 4; ++r)
                Pt[wave][lhi * 4 + r][nb * 16 + llo] = (bf16_t)p[nb][r];

#pragma unroll
        for (int st = 0; st < 2; ++st) {
            bf16x8 pf = *(const bf16x8*)&Pt[wave][llo][st * 32 + lhi * 8];
#pragma unroll
            for (int d = 0; d < 4; ++d) {
                bf16x8 vf = *(const bf16x8*)&Vt[d * 16 + llo][st * 32 + lhi * 8];
                oacc[d] = __builtin_amdgcn_mfma_f32_16x16x32_bf16(pf, vf, oacc[d], 0, 0, 0);
            }
        }
    }

    const int q0 = qb * 64 + wave * 16 + lhi * 4;
#pragma unroll
    for (int r = 0; r < 4; ++r) {
        const float inv = 1.0f / lrun[r];
        const size_t orow = (size_t)(b * SEQ + q0 + r) * DIM + h * 64;
#pragma unroll
        for (int d = 0; d < 4; ++d)
            Oout[orow + d * 16 + llo] = (bf16_t)(oacc[d][r] * inv);
    }
}

// ---------------- launch ----------------

extern "C" void kernel_launch(void* const* d_in, const int* in_sizes, int n_in,
                              void* d_out, int out_size, void* d_ws, size_t ws_size,
                              hipStream_t stream) {
    (void)in_sizes; (void)n_in; (void)out_size; (void)ws_size;
    const float* batch   = (const float*)d_in[0];
    const float* W_qkv   = (const float*)d_in[1];
    const float* u_qkv   = (const float*)d_in[2];
    const float* sg_qkv  = (const float*)d_in[3];
    const float* W_proj  = (const float*)d_in[4];
    const float* u_proj  = (const float*)d_in[5];
    const float* sg_proj = (const float*)d_in[6];
    float* out = (float*)d_out;

    char* ws = (char*)d_ws;
    size_t off = 0;
    auto alloc = [&](size_t bytes) -> void* {
        void* p = ws + off;
        off = (off + bytes + 255) & ~(size_t)255;
        return p;
    };
    float* y_q    = (float*)alloc(1024 * 4);
    float* part_q = (float*)alloc(8 * 3072 * 4);
    float* sc_q   = (float*)alloc(4);
    float* y_p    = (float*)alloc(1024 * 4);
    float* part_p = (float*)alloc(8 * 1024 * 4);
    float* sc_p   = (float*)alloc(4);
    bf16_t* Xb   = (bf16_t*)alloc((size_t)MROWS * DIM * 2);
    bf16_t* Wtq  = (bf16_t*)alloc((size_t)3 * DIM * DIM * 2);
    bf16_t* Wtp  = (bf16_t*)alloc((size_t)DIM * DIM * 2);
    bf16_t* QKVb = (bf16_t*)alloc((size_t)MROWS * 3 * DIM * 2);
    bf16_t* AOb  = (bf16_t*)alloc((size_t)MROWS * DIM * 2);

    // sigma_qkv: y = W@u [1024]; scale = sp*||y||/||W^T y||
    matvec_rows<<<1024, 256, 0, stream>>>(W_qkv, u_qkv, y_q, 3072);
    matvec_cols_part<<<dim3(12, 8), 256, 0, stream>>>(W_qkv, y_q, part_q, 3072);
    norm_scale<<<1, 1024, 0, stream>>>(y_q, 1024, part_q, 3072, sg_qkv, sc_q);

    // sigma_proj
    matvec_rows<<<1024, 256, 0, stream>>>(W_proj, u_proj, y_p, 1024);
    matvec_cols_part<<<dim3(4, 8), 256, 0, stream>>>(W_proj, y_p, part_p, 1024);
    norm_scale<<<1, 1024, 0, stream>>>(y_p, 1024, part_p, 1024, sg_proj, sc_p);

    // conversions
    convert_x<<<(MROWS * DIM) / (256 * 4), 256, 0, stream>>>(batch, Xb, MROWS * DIM);
    convert_wt<<<dim3(3 * DIM / 32, DIM / 32), 256, 0, stream>>>(W_qkv, Wtq, sc_q, DIM, 3 * DIM);
    convert_wt<<<dim3(DIM / 32, DIM / 32), 256, 0, stream>>>(W_proj, Wtp, sc_p, DIM, DIM);

    // QKV = Xb @ (s*W_qkv)
    gemm_bf16_128<1><<<dim3(3 * DIM / 128, MROWS / 128), 256, 0, stream>>>(
        Xb, Wtq, QKVb, nullptr, MROWS, 3 * DIM, DIM);

    // attention
    flash_attn<<<dim3(SEQ / 64, BATCH * HEADS), 256, 0, stream>>>(QKVb, AOb);

    // out = AOb @ (s*W_proj)
    gemm_bf16_128<0><<<dim3(DIM / 128, MROWS / 128), 256, 0, stream>>>(
        AOb, Wtp, nullptr, out, MROWS, DIM, DIM);
}

// Round 3
// 241.460 us; speedup vs baseline: 3.0241x; 1.1645x over previous
//
#include <hip/hip_runtime.h>
#include <hip/hip_bf16.h>

#define DIM 1024
#define HEADS 16
#define BATCH 2
#define SEQ 2048
#define MROWS (BATCH*SEQ)   // 4096
#define KVB 64
#define QBLK 128

typedef __bf16 bf16_t;
typedef __bf16 bf16x8 __attribute__((ext_vector_type(8)));
typedef __bf16 bf16x4 __attribute__((ext_vector_type(4)));
typedef float  f32x4  __attribute__((ext_vector_type(4)));

__device__ inline float waveReduceSum(float v) {
#pragma unroll
    for (int off = 32; off > 0; off >>= 1) v += __shfl_down(v, off, 64);
    return v;
}

// async global->LDS 16B: LDS dest is wave-uniform base; HW writes base + lane*16.
__device__ inline void gload_lds16(const bf16_t* g, bf16_t* l) {
    __builtin_amdgcn_global_load_lds(
        (const __attribute__((address_space(1))) void*)g,
        (__attribute__((address_space(3))) void*)l,
        16, 0, 0);
}

// ---------------- power iteration: scale = sp * ||W@u|| / ||W^T(W@u)|| --------

__global__ __launch_bounds__(256) void matvec_rows(const float* __restrict__ W,
                                                   const float* __restrict__ x,
                                                   float* __restrict__ y, int C) {
    const int row = blockIdx.x;
    const float* Wr = W + (size_t)row * C;
    float acc = 0.f;
    for (int j = threadIdx.x; j < C; j += 256) acc += Wr[j] * x[j];
    __shared__ float red[4];
    float s = waveReduceSum(acc);
    if ((threadIdx.x & 63) == 0) red[threadIdx.x >> 6] = s;
    __syncthreads();
    if (threadIdx.x == 0) y[row] = red[0] + red[1] + red[2] + red[3];
}

__global__ __launch_bounds__(256) void matvec_cols_part(const float* __restrict__ W,
                                                        const float* __restrict__ y,
                                                        float* __restrict__ part, int C) {
    const int j = blockIdx.x * 256 + threadIdx.x;
    const int i0 = blockIdx.y * 128;
    float acc = 0.f;
#pragma unroll 4
    for (int i = i0; i < i0 + 128; ++i) acc += W[(size_t)i * C + j] * y[i];
    part[(size_t)blockIdx.y * C + j] = acc;
}

__global__ __launch_bounds__(1024) void norm_scale(const float* __restrict__ y, int R,
                                                   const float* __restrict__ part, int C,
                                                   const float* __restrict__ sp,
                                                   float* __restrict__ scale) {
    float accY = 0.f, accZ = 0.f;
    for (int i = threadIdx.x; i < R; i += 1024) { float t = y[i]; accY += t * t; }
    for (int j = threadIdx.x; j < C; j += 1024) {
        float z = 0.f;
#pragma unroll
        for (int p = 0; p < 8; ++p) z += part[(size_t)p * C + j];
        accZ += z * z;
    }
    __shared__ float redY[16], redZ[16];
    float sy = waveReduceSum(accY), sz = waveReduceSum(accZ);
    const int w = threadIdx.x >> 6;
    if ((threadIdx.x & 63) == 0) { redY[w] = sy; redZ[w] = sz; }
    __syncthreads();
    if (threadIdx.x == 0) {
        float SY = 0.f, SZ = 0.f;
#pragma unroll
        for (int i = 0; i < 16; ++i) { SY += redY[i]; SZ += redZ[i]; }
        scale[0] = sp[0] * sqrtf(SY) / sqrtf(SZ);
    }
}

// ---------------- conversions ----------------

__global__ __launch_bounds__(256) void convert_x(const float* __restrict__ X,
                                                 bf16_t* __restrict__ Xb, int n) {
    int i = (blockIdx.x * 256 + threadIdx.x) * 4;
    if (i + 3 < n) {
        float4 v = *(const float4*)(X + i);
        bf16x4 o;
        o[0] = (bf16_t)v.x; o[1] = (bf16_t)v.y; o[2] = (bf16_t)v.z; o[3] = (bf16_t)v.w;
        *(bf16x4*)(Xb + i) = o;
    }
}

__global__ __launch_bounds__(256) void convert_wt(const float* __restrict__ W,
                                                  bf16_t* __restrict__ Wt,
                                                  const float* __restrict__ scalep,
                                                  int R, int C) {
    __shared__ float t[32][33];
    const float s = *scalep;
    const int bx = blockIdx.x * 32;
    const int by = blockIdx.y * 32;
    const int tx = threadIdx.x & 31;
    const int ty = threadIdx.x >> 5;
#pragma unroll
    for (int j = ty; j < 32; j += 8)
        t[j][tx] = W[(size_t)(by + j) * C + bx + tx];
    __syncthreads();
#pragma unroll
    for (int j = ty; j < 32; j += 8)
        Wt[(size_t)(bx + j) * R + by + tx] = (bf16_t)(t[tx][j] * s);
}

// ---------------- bf16 MFMA GEMM (m97 structure) ----------------

template <int OUT_BF16>
__global__ __launch_bounds__(256) void gemm_bf16_128(const bf16_t* __restrict__ A,
                                                     const bf16_t* __restrict__ Bt,
                                                     bf16_t* __restrict__ Cb,
                                                     float* __restrict__ Cf,
                                                     int M, int N, int K) {
    __shared__ __align__(16) bf16_t tA[128 * 32];
    __shared__ __align__(16) bf16_t tB[128 * 32];
    const int tid = threadIdx.x;
    const int wave = tid >> 6, lane = tid & 63, lhi = lane >> 4, llo = lane & 15;
    const int wr = wave >> 1, wc = wave & 1;
    const int rowBase = blockIdx.y * 128, colBase = blockIdx.x * 128;

    const int srow = wave * 16 + (lane >> 2);
    const int scol = (lane & 3) * 8;
    const bf16_t* pA0 = &A[(size_t)(rowBase + srow) * K + scol];
    const bf16_t* pA1 = &A[(size_t)(rowBase + 64 + srow) * K + scol];
    const bf16_t* pB0 = &Bt[(size_t)(colBase + srow) * K + scol];
    const bf16_t* pB1 = &Bt[(size_t)(colBase + 64 + srow) * K + scol];
    bf16_t* dA0 = tA + wave * 512;
    bf16_t* dA1 = tA + 2048 + wave * 512;
    bf16_t* dB0 = tB + wave * 512;
    bf16_t* dB1 = tB + 2048 + wave * 512;

    f32x4 acc[4][4] = {};
    for (int k0 = 0; k0 < K; k0 += 32) {
        __syncthreads();
        gload_lds16(pA0 + k0, dA0);
        gload_lds16(pA1 + k0, dA1);
        gload_lds16(pB0 + k0, dB0);
        gload_lds16(pB1 + k0, dB1);
        __syncthreads();
        bf16x8 af[4], bfr[4];
#pragma unroll
        for (int m = 0; m < 4; ++m)
            af[m] = *(const bf16x8*)&tA[(wr * 64 + m * 16 + llo) * 32 + lhi * 8];
#pragma unroll
        for (int n = 0; n < 4; ++n)
            bfr[n] = *(const bf16x8*)&tB[(wc * 64 + n * 16 + llo) * 32 + lhi * 8];
#pragma unroll
        for (int m = 0; m < 4; ++m)
#pragma unroll
            for (int n = 0; n < 4; ++n)
                acc[m][n] = __builtin_amdgcn_mfma_f32_16x16x32_bf16(af[m], bfr[n], acc[m][n], 0, 0, 0);
    }
#pragma unroll
    for (int m = 0; m < 4; ++m) {
        const int row0 = rowBase + wr * 64 + m * 16 + lhi * 4;
#pragma unroll
        for (int n = 0; n < 4; ++n) {
            const int col = colBase + wc * 64 + n * 16 + llo;
#pragma unroll
            for (int r2 = 0; r2 < 4; ++r2) {
                const size_t idx = (size_t)(row0 + r2) * N + col;
                if (OUT_BF16) Cb[idx] = (bf16_t)acc[m][n][r2];
                else          Cf[idx] = acc[m][n][r2];
            }
        }
    }
}

// ---------------- causal flash attention, QBLK=128, dbuf K/V, swizzled LDS ----
// grid: (SEQ/128, BATCH*HEADS), block 256 (4 waves x 32 q-rows each).

__global__ __launch_bounds__(256) void flash_attn(const bf16_t* __restrict__ QKV,
                                                  bf16_t* __restrict__ Oout) {
    const int qblk = blockIdx.x;
    const int bh = blockIdx.y;
    const int b = bh >> 4, h = bh & 15;
    const int tid = threadIdx.x;
    const int wave = tid >> 6, lane = tid & 63, lhi = lane >> 4, llo = lane & 15;
    const size_t rstride = 3 * DIM;
    const bf16_t* Qp = QKV + (size_t)b * SEQ * rstride + h * 64;
    const bf16_t* Kp = Qp + DIM;
    const bf16_t* Vp = Qp + 2 * DIM;

    // K: linear [64][64] with content swizzle col^8*(row&7) (via pre-swizzled src)
    // V: transposed [d][kv], content swizzle r^8*(c&7)
    __shared__ __align__(16) bf16_t Kt[2][KVB * 64];
    __shared__ __align__(16) bf16_t Vt[2][KVB * 64];
    __shared__ __align__(16) bf16_t Pt[4][32][72];

    const int qBase = qblk * QBLK;
    const int swz = 8 * (llo & 7);

    // Q fragments (registers for the whole kernel)
    bf16x8 qf[2][2];
#pragma unroll
    for (int m = 0; m < 2; ++m)
#pragma unroll
        for (int st = 0; st < 2; ++st)
            qf[m][st] = *(const bf16x8*)&Qp[(size_t)(qBase + wave * 32 + m * 16 + llo) * rstride + st * 32 + lhi * 8];

    // staging helpers
    const int krr = lane >> 3;
    const int ksrc = 8 * ((lane & 7) ^ krr);
    auto stageK = [&](int kt, int buf) {
#pragma unroll
        for (int p = 0; p < 2; ++p)
            gload_lds16(&Kp[(size_t)(kt * KVB + p * 32 + wave * 8 + krr) * rstride + ksrc],
                        &Kt[buf][p * 2048 + wave * 512]);
    };

    bf16x8 vreg0, vreg1;
    auto loadV = [&](int kt) {
        const bf16_t* g = &Vp[(size_t)(kt * KVB + lane) * rstride + wave * 16];
        vreg0 = *(const bf16x8*)g;
        vreg1 = *(const bf16x8*)(g + 8);
    };
    auto scatterV = [&](int buf) {
        const int c0 = wave * 16;
#pragma unroll
        for (int j = 0; j < 8; ++j) {
            Vt[buf][(c0 + j) * 64 + (lane ^ (8 * j))] = vreg0[j];
            Vt[buf][(c0 + 8 + j) * 64 + (lane ^ (8 * j))] = vreg1[j];
        }
    };

    f32x4 oacc[2][4] = {};
    float mrun[2][4], lrun[2][4];
#pragma unroll
    for (int m = 0; m < 2; ++m)
#pragma unroll
        for (int r = 0; r < 4; ++r) { mrun[m][r] = -1e30f; lrun[m][r] = 0.f; }
    const float scl = 0.125f;

    const int nt = 2 * qblk + 2;
    const int qmaxw = qBase + wave * 32 + 31;

    // prologue: stage tile 0
    stageK(0, 0);
    loadV(0);
    scatterV(0);
    __syncthreads();

    int cur = 0;
    for (int kt = 0; kt < nt; ++kt) {
        const bool havenext = (kt + 1) < nt;
        if (havenext) { stageK(kt + 1, cur ^ 1); loadV(kt + 1); }

        if (kt * KVB <= qmaxw) {
            // S = Q K^T
            f32x4 s[2][4] = {};
#pragma unroll
            for (int nb = 0; nb < 4; ++nb)
#pragma unroll
                for (int st = 0; st < 2; ++st) {
                    bf16x8 kf = *(const bf16x8*)&Kt[cur][(nb * 16 + llo) * 64 + ((st * 32 + lhi * 8) ^ swz)];
                    s[0][nb] = __builtin_amdgcn_mfma_f32_16x16x32_bf16(qf[0][st], kf, s[0][nb], 0, 0, 0);
                    s[1][nb] = __builtin_amdgcn_mfma_f32_16x16x32_bf16(qf[1][st], kf, s[1][nb], 0, 0, 0);
                }

            // softmax per m-subtile
#pragma unroll
            for (int m = 0; m < 2; ++m) {
                const int q0 = qBase + wave * 32 + m * 16 + lhi * 4;
                const bool needmask = (kt * KVB + 63) > (qBase + wave * 32 + m * 16);
                float p[4][4];
                float mt[4] = {-1e30f, -1e30f, -1e30f, -1e30f};
#pragma unroll
                for (int nb = 0; nb < 4; ++nb)
#pragma unroll
                    for (int r = 0; r < 4; ++r) {
                        float sv = s[m][nb][r] * scl;
                        if (needmask && (kt * KVB + nb * 16 + llo > q0 + r)) sv = -1e30f;
                        p[nb][r] = sv;
                        mt[r] = fmaxf(mt[r], sv);
                    }
#pragma unroll
                for (int off = 1; off < 16; off <<= 1)
#pragma unroll
                    for (int r = 0; r < 4; ++r) mt[r] = fmaxf(mt[r], __shfl_xor(mt[r], off, 64));

                float alpha[4];
#pragma unroll
                for (int r = 0; r < 4; ++r) {
                    float mnew = fmaxf(mrun[m][r], mt[r]);
                    alpha[r] = __expf(mrun[m][r] - mnew);
                    mrun[m][r] = mnew;
                }
                float lt[4] = {0.f, 0.f, 0.f, 0.f};
#pragma unroll
                for (int nb = 0; nb < 4; ++nb)
#pragma unroll
                    for (int r = 0; r < 4; ++r) {
                        float e = __expf(p[nb][r] - mrun[m][r]);
                        p[nb][r] = e;
                        lt[r] += e;
                    }
#pragma unroll
                for (int off = 1; off < 16; off <<= 1)
#pragma unroll
                    for (int r = 0; r < 4; ++r) lt[r] += __shfl_xor(lt[r], off, 64);
#pragma unroll
                for (int r = 0; r < 4; ++r) lrun[m][r] = lrun[m][r] * alpha[r] + lt[r];
#pragma unroll
                for (int d = 0; d < 4; ++d)
#pragma unroll
                    for (int r = 0; r < 4; ++r) oacc[m][d][r] *= alpha[r];

#pragma unroll
                for (int nb = 0; nb < 4; ++nb)
#pragma unroll
                    for (int r = 0; r < 4; ++r)
                        Pt[wave][m * 16 + lhi * 4 + r][nb * 16 + llo] = (bf16_t)p[nb][r];
            }

            // O += P V
            bf16x8 pf[2][2];
#pragma unroll
            for (int m = 0; m < 2; ++m)
#pragma unroll
                for (int st = 0; st < 2; ++st)
                    pf[m][st] = *(const bf16x8*)&Pt[wave][m * 16 + llo][st * 32 + lhi * 8];
#pragma unroll
            for (int st = 0; st < 2; ++st)
#pragma unroll
                for (int d = 0; d < 4; ++d) {
                    bf16x8 vf = *(const bf16x8*)&Vt[cur][(d * 16 + llo) * 64 + ((st * 32 + lhi * 8) ^ swz)];
                    oacc[0][d] = __builtin_amdgcn_mfma_f32_16x16x32_bf16(pf[0][st], vf, oacc[0][d], 0, 0, 0);
                    oacc[1][d] = __builtin_amdgcn_mfma_f32_16x16x32_bf16(pf[1][st], vf, oacc[1][d], 0, 0, 0);
                }
        }

        if (havenext) scatterV(cur ^ 1);
        __syncthreads();
        cur ^= 1;
    }

    // epilogue
#pragma unroll
    for (int m = 0; m < 2; ++m)
#pragma unroll
        for (int r = 0; r < 4; ++r) {
            const int q = qBase + wave * 32 + m * 16 + lhi * 4 + r;
            const float inv = 1.0f / lrun[m][r];
            const size_t orow = (size_t)(b * SEQ + q) * DIM + h * 64;
#pragma unroll
            for (int d = 0; d < 4; ++d)
                Oout[orow + d * 16 + llo] = (bf16_t)(oacc[m][d][r] * inv);
        }
}

// ---------------- launch ----------------

extern "C" void kernel_launch(void* const* d_in, const int* in_sizes, int n_in,
                              void* d_out, int out_size, void* d_ws, size_t ws_size,
                              hipStream_t stream) {
    (void)in_sizes; (void)n_in; (void)out_size; (void)ws_size;
    const float* batch   = (const float*)d_in[0];
    const float* W_qkv   = (const float*)d_in[1];
    const float* u_qkv   = (const float*)d_in[2];
    const float* sg_qkv  = (const float*)d_in[3];
    const float* W_proj  = (const float*)d_in[4];
    const float* u_proj  = (const float*)d_in[5];
    const float* sg_proj = (const float*)d_in[6];
    float* out = (float*)d_out;

    char* ws = (char*)d_ws;
    size_t off = 0;
    auto alloc = [&](size_t bytes) -> void* {
        void* p = ws + off;
        off = (off + bytes + 255) & ~(size_t)255;
        return p;
    };
    float* y_q    = (float*)alloc(1024 * 4);
    float* part_q = (float*)alloc(8 * 3072 * 4);
    float* sc_q   = (float*)alloc(4);
    float* y_p    = (float*)alloc(1024 * 4);
    float* part_p = (float*)alloc(8 * 1024 * 4);
    float* sc_p   = (float*)alloc(4);
    bf16_t* Xb   = (bf16_t*)alloc((size_t)MROWS * DIM * 2);
    bf16_t* Wtq  = (bf16_t*)alloc((size_t)3 * DIM * DIM * 2);
    bf16_t* Wtp  = (bf16_t*)alloc((size_t)DIM * DIM * 2);
    bf16_t* QKVb = (bf16_t*)alloc((size_t)MROWS * 3 * DIM * 2);
    bf16_t* AOb  = (bf16_t*)alloc((size_t)MROWS * DIM * 2);

    // sigma_qkv: y = W@u; scale = sp*||y||/||W^T y||
    matvec_rows<<<1024, 256, 0, stream>>>(W_qkv, u_qkv, y_q, 3072);
    matvec_cols_part<<<dim3(12, 8), 256, 0, stream>>>(W_qkv, y_q, part_q, 3072);
    norm_scale<<<1, 1024, 0, stream>>>(y_q, 1024, part_q, 3072, sg_qkv, sc_q);

    // sigma_proj
    matvec_rows<<<1024, 256, 0, stream>>>(W_proj, u_proj, y_p, 1024);
    matvec_cols_part<<<dim3(4, 8), 256, 0, stream>>>(W_proj, y_p, part_p, 1024);
    norm_scale<<<1, 1024, 0, stream>>>(y_p, 1024, part_p, 1024, sg_proj, sc_p);

    // conversions
    convert_x<<<(MROWS * DIM) / (256 * 4), 256, 0, stream>>>(batch, Xb, MROWS * DIM);
    convert_wt<<<dim3(3 * DIM / 32, DIM / 32), 256, 0, stream>>>(W_qkv, Wtq, sc_q, DIM, 3 * DIM);
    convert_wt<<<dim3(DIM / 32, DIM / 32), 256, 0, stream>>>(W_proj, Wtp, sc_p, DIM, DIM);

    // QKV = Xb @ (s*W_qkv)
    gemm_bf16_128<1><<<dim3(3 * DIM / 128, MROWS / 128), 256, 0, stream>>>(
        Xb, Wtq, QKVb, nullptr, MROWS, 3 * DIM, DIM);

    // attention
    flash_attn<<<dim3(SEQ / QBLK, BATCH * HEADS), 256, 0, stream>>>(QKVb, AOb);

    // out = AOb @ (s*W_proj)
    gemm_bf16_128<0><<<dim3(DIM / 128, MROWS / 128), 256, 0, stream>>>(
        AOb, Wtp, nullptr, out, MROWS, DIM, DIM);
}

// Round 7
// 223.500 us; speedup vs baseline: 3.2671x; 1.0804x over previous
//
#include <hip/hip_runtime.h>
#include <hip/hip_bf16.h>

#define DIM 1024
#define HEADS 16
#define BATCH 2
#define SEQ 2048
#define MROWS (BATCH*SEQ)   // 4096
#define KVB 64
#define QBLK 128

typedef __bf16 bf16_t;
typedef __bf16 bf16x8 __attribute__((ext_vector_type(8)));
typedef __bf16 bf16x4 __attribute__((ext_vector_type(4)));
typedef float  f32x4  __attribute__((ext_vector_type(4)));

__device__ inline float waveReduceSum(float v) {
#pragma unroll
    for (int off = 32; off > 0; off >>= 1) v += __shfl_down(v, off, 64);
    return v;
}

// async global->LDS 16B: LDS dest is wave-uniform base; HW writes base + lane*16.
__device__ inline void gload_lds16(const bf16_t* g, bf16_t* l) {
    __builtin_amdgcn_global_load_lds(
        (const __attribute__((address_space(1))) void*)g,
        (__attribute__((address_space(3))) void*)l,
        16, 0, 0);
}

// ---------------- power iteration: scale = sp * ||W@u|| / ||W^T(W@u)|| --------

__global__ __launch_bounds__(256) void matvec_rows(const float* __restrict__ W,
                                                   const float* __restrict__ x,
                                                   float* __restrict__ y, int C) {
    const int row = blockIdx.x;
    const float* Wr = W + (size_t)row * C;
    float acc = 0.f;
    for (int j = threadIdx.x; j < C; j += 256) acc += Wr[j] * x[j];
    __shared__ float red[4];
    float s = waveReduceSum(acc);
    if ((threadIdx.x & 63) == 0) red[threadIdx.x >> 6] = s;
    __syncthreads();
    if (threadIdx.x == 0) y[row] = red[0] + red[1] + red[2] + red[3];
}

__global__ __launch_bounds__(256) void matvec_cols_part(const float* __restrict__ W,
                                                        const float* __restrict__ y,
                                                        float* __restrict__ part, int C) {
    const int j = blockIdx.x * 256 + threadIdx.x;
    const int i0 = blockIdx.y * 128;
    float acc = 0.f;
#pragma unroll 4
    for (int i = i0; i < i0 + 128; ++i) acc += W[(size_t)i * C + j] * y[i];
    part[(size_t)blockIdx.y * C + j] = acc;
}

__global__ __launch_bounds__(1024) void norm_scale(const float* __restrict__ y, int R,
                                                   const float* __restrict__ part, int C,
                                                   const float* __restrict__ sp,
                                                   float* __restrict__ scale) {
    float accY = 0.f, accZ = 0.f;
    for (int i = threadIdx.x; i < R; i += 1024) { float t = y[i]; accY += t * t; }
    for (int j = threadIdx.x; j < C; j += 1024) {
        float z = 0.f;
#pragma unroll
        for (int p = 0; p < 8; ++p) z += part[(size_t)p * C + j];
        accZ += z * z;
    }
    __shared__ float redY[16], redZ[16];
    float sy = waveReduceSum(accY), sz = waveReduceSum(accZ);
    const int w = threadIdx.x >> 6;
    if ((threadIdx.x & 63) == 0) { redY[w] = sy; redZ[w] = sz; }
    __syncthreads();
    if (threadIdx.x == 0) {
        float SY = 0.f, SZ = 0.f;
#pragma unroll
        for (int i = 0; i < 16; ++i) { SY += redY[i]; SZ += redZ[i]; }
        scale[0] = sp[0] * sqrtf(SY) / sqrtf(SZ);
    }
}

// ---------------- conversions ----------------

__global__ __launch_bounds__(256) void convert_x(const float* __restrict__ X,
                                                 bf16_t* __restrict__ Xb, int n) {
    int i = (blockIdx.x * 256 + threadIdx.x) * 4;
    if (i + 3 < n) {
        float4 v = *(const float4*)(X + i);
        bf16x4 o;
        o[0] = (bf16_t)v.x; o[1] = (bf16_t)v.y; o[2] = (bf16_t)v.z; o[3] = (bf16_t)v.w;
        *(bf16x4*)(Xb + i) = o;
    }
}

__global__ __launch_bounds__(256) void convert_wt(const float* __restrict__ W,
                                                  bf16_t* __restrict__ Wt,
                                                  const float* __restrict__ scalep,
                                                  int R, int C) {
    __shared__ float t[32][33];
    const float s = *scalep;
    const int bx = blockIdx.x * 32;
    const int by = blockIdx.y * 32;
    const int tx = threadIdx.x & 31;
    const int ty = threadIdx.x >> 5;
#pragma unroll
    for (int j = ty; j < 32; j += 8)
        t[j][tx] = W[(size_t)(by + j) * C + bx + tx];
    __syncthreads();
#pragma unroll
    for (int j = ty; j < 32; j += 8)
        Wt[(size_t)(bx + j) * R + by + tx] = (bf16_t)(t[tx][j] * s);
}

// ---------------- bf16 MFMA GEMM (m97 structure) ----------------

template <int OUT_BF16>
__global__ __launch_bounds__(256) void gemm_bf16_128(const bf16_t* __restrict__ A,
                                                     const bf16_t* __restrict__ Bt,
                                                     bf16_t* __restrict__ Cb,
                                                     float* __restrict__ Cf,
                                                     int M, int N, int K) {
    __shared__ __align__(16) bf16_t tA[128 * 32];
    __shared__ __align__(16) bf16_t tB[128 * 32];
    const int tid = threadIdx.x;
    const int wave = tid >> 6, lane = tid & 63, lhi = lane >> 4, llo = lane & 15;
    const int wr = wave >> 1, wc = wave & 1;
    const int rowBase = blockIdx.y * 128, colBase = blockIdx.x * 128;

    const int srow = wave * 16 + (lane >> 2);
    const int scol = (lane & 3) * 8;
    const bf16_t* pA0 = &A[(size_t)(rowBase + srow) * K + scol];
    const bf16_t* pA1 = &A[(size_t)(rowBase + 64 + srow) * K + scol];
    const bf16_t* pB0 = &Bt[(size_t)(colBase + srow) * K + scol];
    const bf16_t* pB1 = &Bt[(size_t)(colBase + 64 + srow) * K + scol];
    bf16_t* dA0 = tA + wave * 512;
    bf16_t* dA1 = tA + 2048 + wave * 512;
    bf16_t* dB0 = tB + wave * 512;
    bf16_t* dB1 = tB + 2048 + wave * 512;

    f32x4 acc[4][4] = {};
    for (int k0 = 0; k0 < K; k0 += 32) {
        __syncthreads();
        gload_lds16(pA0 + k0, dA0);
        gload_lds16(pA1 + k0, dA1);
        gload_lds16(pB0 + k0, dB0);
        gload_lds16(pB1 + k0, dB1);
        __syncthreads();
        bf16x8 af[4], bfr[4];
#pragma unroll
        for (int m = 0; m < 4; ++m)
            af[m] = *(const bf16x8*)&tA[(wr * 64 + m * 16 + llo) * 32 + lhi * 8];
#pragma unroll
        for (int n = 0; n < 4; ++n)
            bfr[n] = *(const bf16x8*)&tB[(wc * 64 + n * 16 + llo) * 32 + lhi * 8];
#pragma unroll
        for (int m = 0; m < 4; ++m)
#pragma unroll
            for (int n = 0; n < 4; ++n)
                acc[m][n] = __builtin_amdgcn_mfma_f32_16x16x32_bf16(af[m], bfr[n], acc[m][n], 0, 0, 0);
    }
#pragma unroll
    for (int m = 0; m < 4; ++m) {
        const int row0 = rowBase + wr * 64 + m * 16 + lhi * 4;
#pragma unroll
        for (int n = 0; n < 4; ++n) {
            const int col = colBase + wc * 64 + n * 16 + llo;
#pragma unroll
            for (int r2 = 0; r2 < 4; ++r2) {
                const size_t idx = (size_t)(row0 + r2) * N + col;
                if (OUT_BF16) Cb[idx] = (bf16_t)acc[m][n][r2];
                else          Cf[idx] = acc[m][n][r2];
            }
        }
    }
}

// ---------------- causal flash attention (r2-proven structure) ----------------
// grid: (SEQ/128, BATCH*HEADS), block 256 (4 waves x 32 q-rows).
// LPT remap: colocated blocks (id, id+256) get qblk summing to 15 -> per-CU
// work balanced. Coverage is a permutation of (bh, qblk); semantics unchanged.

__global__ __launch_bounds__(256) void flash_attn(const bf16_t* __restrict__ QKV,
                                                  bf16_t* __restrict__ Oout) {
    const int bh = blockIdx.y;
    const int qblk = (bh < 16) ? blockIdx.x : (15 - blockIdx.x);
    const int b = bh >> 4, h = bh & 15;
    const int tid = threadIdx.x;
    const int wave = tid >> 6, lane = tid & 63, lhi = lane >> 4, llo = lane & 15;
    const size_t rstride = 3 * DIM;
    const bf16_t* Qp = QKV + (size_t)b * SEQ * rstride + h * 64;
    const bf16_t* Kp = Qp + DIM;
    const bf16_t* Vp = Qp + 2 * DIM;

    __shared__ __align__(16) bf16_t Kt[2][KVB * 64];
    __shared__ __align__(16) bf16_t Vt[2][KVB * 64];
    __shared__ __align__(16) bf16_t Pt[4][32][72];

    const int qBase = qblk * QBLK;
    const int swz = 8 * (llo & 7);

    // Q fragments (registers for the whole kernel)
    bf16x8 qf[2][2];
#pragma unroll
    for (int m = 0; m < 2; ++m)
#pragma unroll
        for (int st = 0; st < 2; ++st)
            qf[m][st] = *(const bf16x8*)&Qp[(size_t)(qBase + wave * 32 + m * 16 + llo) * rstride + st * 32 + lhi * 8];

    // staging helpers
    const int krr = lane >> 3;
    const int ksrc = 8 * ((lane & 7) ^ krr);
    auto stageK = [&](int kt, int buf) {
#pragma unroll
        for (int p = 0; p < 2; ++p)
            gload_lds16(&Kp[(size_t)(kt * KVB + p * 32 + wave * 8 + krr) * rstride + ksrc],
                        &Kt[buf][p * 2048 + wave * 512]);
    };

    bf16x8 vreg0, vreg1;
    auto loadV = [&](int kt) {
        const bf16_t* g = &Vp[(size_t)(kt * KVB + lane) * rstride + wave * 16];
        vreg0 = *(const bf16x8*)g;
        vreg1 = *(const bf16x8*)(g + 8);
    };
    auto scatterV = [&](int buf) {
        const int c0 = wave * 16;
#pragma unroll
        for (int j = 0; j < 8; ++j) {
            Vt[buf][(c0 + j) * 64 + (lane ^ (8 * j))] = vreg0[j];
            Vt[buf][(c0 + 8 + j) * 64 + (lane ^ (8 * j))] = vreg1[j];
        }
    };

    f32x4 oacc[2][4] = {};
    float mrun[2][4], lrun[2][4];
#pragma unroll
    for (int m = 0; m < 2; ++m)
#pragma unroll
        for (int r = 0; r < 4; ++r) { mrun[m][r] = -1e30f; lrun[m][r] = 0.f; }
    const float scl = 0.125f;

    const int nt = 2 * qblk + 2;
    const int qmaxw = qBase + wave * 32 + 31;

    // prologue: stage tile 0
    stageK(0, 0);
    loadV(0);
    scatterV(0);
    __syncthreads();

    int cur = 0;
    for (int kt = 0; kt < nt; ++kt) {
        const bool havenext = (kt + 1) < nt;
        if (havenext) { stageK(kt + 1, cur ^ 1); loadV(kt + 1); }

        if (kt * KVB <= qmaxw) {
            // S = Q K^T
            f32x4 s[2][4] = {};
#pragma unroll
            for (int nb = 0; nb < 4; ++nb)
#pragma unroll
                for (int st = 0; st < 2; ++st) {
                    bf16x8 kf = *(const bf16x8*)&Kt[cur][(nb * 16 + llo) * 64 + ((st * 32 + lhi * 8) ^ swz)];
                    s[0][nb] = __builtin_amdgcn_mfma_f32_16x16x32_bf16(qf[0][st], kf, s[0][nb], 0, 0, 0);
                    s[1][nb] = __builtin_amdgcn_mfma_f32_16x16x32_bf16(qf[1][st], kf, s[1][nb], 0, 0, 0);
                }

            // softmax per m-subtile
#pragma unroll
            for (int m = 0; m < 2; ++m) {
                const int q0 = qBase + wave * 32 + m * 16 + lhi * 4;
                const bool needmask = (kt * KVB + 63) > (qBase + wave * 32 + m * 16);
                float p[4][4];
                float mt[4] = {-1e30f, -1e30f, -1e30f, -1e30f};
#pragma unroll
                for (int nb = 0; nb < 4; ++nb)
#pragma unroll
                    for (int r = 0; r < 4; ++r) {
                        float sv = s[m][nb][r] * scl;
                        if (needmask && (kt * KVB + nb * 16 + llo > q0 + r)) sv = -1e30f;
                        p[nb][r] = sv;
                        mt[r] = fmaxf(mt[r], sv);
                    }
#pragma unroll
                for (int off = 1; off < 16; off <<= 1)
#pragma unroll
                    for (int r = 0; r < 4; ++r) mt[r] = fmaxf(mt[r], __shfl_xor(mt[r], off, 64));

                float alpha[4];
#pragma unroll
                for (int r = 0; r < 4; ++r) {
                    float mnew = fmaxf(mrun[m][r], mt[r]);
                    alpha[r] = __expf(mrun[m][r] - mnew);
                    mrun[m][r] = mnew;
                }
                float lt[4] = {0.f, 0.f, 0.f, 0.f};
#pragma unroll
                for (int nb = 0; nb < 4; ++nb)
#pragma unroll
                    for (int r = 0; r < 4; ++r) {
                        float e = __expf(p[nb][r] - mrun[m][r]);
                        p[nb][r] = e;
                        lt[r] += e;
                    }
#pragma unroll
                for (int off = 1; off < 16; off <<= 1)
#pragma unroll
                    for (int r = 0; r < 4; ++r) lt[r] += __shfl_xor(lt[r], off, 64);
#pragma unroll
                for (int r = 0; r < 4; ++r) lrun[m][r] = lrun[m][r] * alpha[r] + lt[r];
#pragma unroll
                for (int d = 0; d < 4; ++d)
#pragma unroll
                    for (int r = 0; r < 4; ++r) oacc[m][d][r] *= alpha[r];

#pragma unroll
                for (int nb = 0; nb < 4; ++nb)
#pragma unroll
                    for (int r = 0; r < 4; ++r)
                        Pt[wave][m * 16 + lhi * 4 + r][nb * 16 + llo] = (bf16_t)p[nb][r];
            }

            // O += P V
            bf16x8 pf[2][2];
#pragma unroll
            for (int m = 0; m < 2; ++m)
#pragma unroll
                for (int st = 0; st < 2; ++st)
                    pf[m][st] = *(const bf16x8*)&Pt[wave][m * 16 + llo][st * 32 + lhi * 8];
#pragma unroll
            for (int st = 0; st < 2; ++st)
#pragma unroll
                for (int d = 0; d < 4; ++d) {
                    bf16x8 vf = *(const bf16x8*)&Vt[cur][(d * 16 + llo) * 64 + ((st * 32 + lhi * 8) ^ swz)];
                    oacc[0][d] = __builtin_amdgcn_mfma_f32_16x16x32_bf16(pf[0][st], vf, oacc[0][d], 0, 0, 0);
                    oacc[1][d] = __builtin_amdgcn_mfma_f32_16x16x32_bf16(pf[1][st], vf, oacc[1][d], 0, 0, 0);
                }
        }

        if (havenext) scatterV(cur ^ 1);
        __syncthreads();
        cur ^= 1;
    }

    // epilogue
#pragma unroll
    for (int m = 0; m < 2; ++m)
#pragma unroll
        for (int r = 0; r < 4; ++r) {
            const int q = qBase + wave * 32 + m * 16 + lhi * 4 + r;
            const float inv = 1.0f / lrun[m][r];
            const size_t orow = (size_t)(b * SEQ + q) * DIM + h * 64;
#pragma unroll
            for (int d = 0; d < 4; ++d)
                Oout[orow + d * 16 + llo] = (bf16_t)(oacc[m][d][r] * inv);
        }
}

// ---------------- launch ----------------

extern "C" void kernel_launch(void* const* d_in, const int* in_sizes, int n_in,
                              void* d_out, int out_size, void* d_ws, size_t ws_size,
                              hipStream_t stream) {
    (void)in_sizes; (void)n_in; (void)out_size; (void)ws_size;
    const float* batch   = (const float*)d_in[0];
    const float* W_qkv   = (const float*)d_in[1];
    const float* u_qkv   = (const float*)d_in[2];
    const float* sg_qkv  = (const float*)d_in[3];
    const float* W_proj  = (const float*)d_in[4];
    const float* u_proj  = (const float*)d_in[5];
    const float* sg_proj = (const float*)d_in[6];
    float* out = (float*)d_out;

    char* ws = (char*)d_ws;
    size_t off = 0;
    auto alloc = [&](size_t bytes) -> void* {
        void* p = ws + off;
        off = (off + bytes + 255) & ~(size_t)255;
        return p;
    };
    float* y_q    = (float*)alloc(1024 * 4);
    float* part_q = (float*)alloc(8 * 3072 * 4);
    float* sc_q   = (float*)alloc(4);
    float* y_p    = (float*)alloc(1024 * 4);
    float* part_p = (float*)alloc(8 * 1024 * 4);
    float* sc_p   = (float*)alloc(4);
    bf16_t* Xb   = (bf16_t*)alloc((size_t)MROWS * DIM * 2);
    bf16_t* Wtq  = (bf16_t*)alloc((size_t)3 * DIM * DIM * 2);
    bf16_t* Wtp  = (bf16_t*)alloc((size_t)DIM * DIM * 2);
    bf16_t* QKVb = (bf16_t*)alloc((size_t)MROWS * 3 * DIM * 2);
    bf16_t* AOb  = (bf16_t*)alloc((size_t)MROWS * DIM * 2);

    matvec_rows<<<1024, 256, 0, stream>>>(W_qkv, u_qkv, y_q, 3072);
    matvec_cols_part<<<dim3(12, 8), 256, 0, stream>>>(W_qkv, y_q, part_q, 3072);
    norm_scale<<<1, 1024, 0, stream>>>(y_q, 1024, part_q, 3072, sg_qkv, sc_q);

    matvec_rows<<<1024, 256, 0, stream>>>(W_proj, u_proj, y_p, 1024);
    matvec_cols_part<<<dim3(4, 8), 256, 0, stream>>>(W_proj, y_p, part_p, 1024);
    norm_scale<<<1, 1024, 0, stream>>>(y_p, 1024, part_p, 1024, sg_proj, sc_p);

    convert_x<<<(MROWS * DIM) / (256 * 4), 256, 0, stream>>>(batch, Xb, MROWS * DIM);
    convert_wt<<<dim3(3 * DIM / 32, DIM / 32), 256, 0, stream>>>(W_qkv, Wtq, sc_q, DIM, 3 * DIM);
    convert_wt<<<dim3(DIM / 32, DIM / 32), 256, 0, stream>>>(W_proj, Wtp, sc_p, DIM, DIM);

    gemm_bf16_128<1><<<dim3(3 * DIM / 128, MROWS / 128), 256, 0, stream>>>(
        Xb, Wtq, QKVb, nullptr, MROWS, 3 * DIM, DIM);

    flash_attn<<<dim3(SEQ / QBLK, BATCH * HEADS), 256, 0, stream>>>(QKVb, AOb);

    gemm_bf16_128<0><<<dim3(DIM / 128, MROWS / 128), 256, 0, stream>>>(
        AOb, Wtp, nullptr, out, MROWS, DIM, DIM);
}

// Round 8
// 206.016 us; speedup vs baseline: 3.5443x; 1.0849x over previous
//
#include <hip/hip_runtime.h>
#include <hip/hip_bf16.h>

#define DIM 1024
#define HEADS 16
#define BATCH 2
#define SEQ 2048
#define MROWS (BATCH*SEQ)   // 4096
#define KVB 64
#define QBLK 128

typedef __bf16 bf16_t;
typedef __bf16 bf16x8 __attribute__((ext_vector_type(8)));
typedef __bf16 bf16x4 __attribute__((ext_vector_type(4)));
typedef float  f32x4  __attribute__((ext_vector_type(4)));

__device__ inline float waveReduceSum(float v) {
#pragma unroll
    for (int off = 32; off > 0; off >>= 1) v += __shfl_down(v, off, 64);
    return v;
}

// async global->LDS 16B: LDS dest is wave-uniform base; HW writes base + lane*16.
__device__ inline void gload_lds16(const bf16_t* g, bf16_t* l) {
    __builtin_amdgcn_global_load_lds(
        (const __attribute__((address_space(1))) void*)g,
        (__attribute__((address_space(3))) void*)l,
        16, 0, 0);
}

// ---------------- power iteration: scale = sp * ||W@u|| / ||W^T(W@u)|| --------

__global__ __launch_bounds__(256) void matvec_rows(const float* __restrict__ W,
                                                   const float* __restrict__ x,
                                                   float* __restrict__ y, int C) {
    const int row = blockIdx.x;
    const float* Wr = W + (size_t)row * C;
    float acc = 0.f;
    for (int j = threadIdx.x; j < C; j += 256) acc += Wr[j] * x[j];
    __shared__ float red[4];
    float s = waveReduceSum(acc);
    if ((threadIdx.x & 63) == 0) red[threadIdx.x >> 6] = s;
    __syncthreads();
    if (threadIdx.x == 0) y[row] = red[0] + red[1] + red[2] + red[3];
}

__global__ __launch_bounds__(256) void matvec_cols_part(const float* __restrict__ W,
                                                        const float* __restrict__ y,
                                                        float* __restrict__ part, int C) {
    const int j = blockIdx.x * 256 + threadIdx.x;
    const int i0 = blockIdx.y * 128;
    float acc = 0.f;
#pragma unroll 4
    for (int i = i0; i < i0 + 128; ++i) acc += W[(size_t)i * C + j] * y[i];
    part[(size_t)blockIdx.y * C + j] = acc;
}

__global__ __launch_bounds__(1024) void norm_scale(const float* __restrict__ y, int R,
                                                   const float* __restrict__ part, int C,
                                                   const float* __restrict__ sp,
                                                   float* __restrict__ scale) {
    float accY = 0.f, accZ = 0.f;
    for (int i = threadIdx.x; i < R; i += 1024) { float t = y[i]; accY += t * t; }
    for (int j = threadIdx.x; j < C; j += 1024) {
        float z = 0.f;
#pragma unroll
        for (int p = 0; p < 8; ++p) z += part[(size_t)p * C + j];
        accZ += z * z;
    }
    __shared__ float redY[16], redZ[16];
    float sy = waveReduceSum(accY), sz = waveReduceSum(accZ);
    const int w = threadIdx.x >> 6;
    if ((threadIdx.x & 63) == 0) { redY[w] = sy; redZ[w] = sz; }
    __syncthreads();
    if (threadIdx.x == 0) {
        float SY = 0.f, SZ = 0.f;
#pragma unroll
        for (int i = 0; i < 16; ++i) { SY += redY[i]; SZ += redZ[i]; }
        scale[0] = sp[0] * sqrtf(SY) / sqrtf(SZ);
    }
}

// ---------------- conversions ----------------

__global__ __launch_bounds__(256) void convert_x(const float* __restrict__ X,
                                                 bf16_t* __restrict__ Xb, int n) {
    int i = (blockIdx.x * 256 + threadIdx.x) * 4;
    if (i + 3 < n) {
        float4 v = *(const float4*)(X + i);
        bf16x4 o;
        o[0] = (bf16_t)v.x; o[1] = (bf16_t)v.y; o[2] = (bf16_t)v.z; o[3] = (bf16_t)v.w;
        *(bf16x4*)(Xb + i) = o;
    }
}

__global__ __launch_bounds__(256) void convert_wt(const float* __restrict__ W,
                                                  bf16_t* __restrict__ Wt,
                                                  const float* __restrict__ scalep,
                                                  int R, int C) {
    __shared__ float t[32][33];
    const float s = *scalep;
    const int bx = blockIdx.x * 32;
    const int by = blockIdx.y * 32;
    const int tx = threadIdx.x & 31;
    const int ty = threadIdx.x >> 5;
#pragma unroll
    for (int j = ty; j < 32; j += 8)
        t[j][tx] = W[(size_t)(by + j) * C + bx + tx];
    __syncthreads();
#pragma unroll
    for (int j = ty; j < 32; j += 8)
        Wt[(size_t)(bx + j) * R + by + tx] = (bf16_t)(t[tx][j] * s);
}

// ---------------- bf16 MFMA GEMM (m97 structure) ----------------

template <int OUT_BF16>
__global__ __launch_bounds__(256) void gemm_bf16_128(const bf16_t* __restrict__ A,
                                                     const bf16_t* __restrict__ Bt,
                                                     bf16_t* __restrict__ Cb,
                                                     float* __restrict__ Cf,
                                                     int M, int N, int K) {
    __shared__ __align__(16) bf16_t tA[128 * 32];
    __shared__ __align__(16) bf16_t tB[128 * 32];
    const int tid = threadIdx.x;
    const int wave = tid >> 6, lane = tid & 63, lhi = lane >> 4, llo = lane & 15;
    const int wr = wave >> 1, wc = wave & 1;
    const int rowBase = blockIdx.y * 128, colBase = blockIdx.x * 128;

    const int srow = wave * 16 + (lane >> 2);
    const int scol = (lane & 3) * 8;
    const bf16_t* pA0 = &A[(size_t)(rowBase + srow) * K + scol];
    const bf16_t* pA1 = &A[(size_t)(rowBase + 64 + srow) * K + scol];
    const bf16_t* pB0 = &Bt[(size_t)(colBase + srow) * K + scol];
    const bf16_t* pB1 = &Bt[(size_t)(colBase + 64 + srow) * K + scol];
    bf16_t* dA0 = tA + wave * 512;
    bf16_t* dA1 = tA + 2048 + wave * 512;
    bf16_t* dB0 = tB + wave * 512;
    bf16_t* dB1 = tB + 2048 + wave * 512;

    f32x4 acc[4][4] = {};
    for (int k0 = 0; k0 < K; k0 += 32) {
        __syncthreads();
        gload_lds16(pA0 + k0, dA0);
        gload_lds16(pA1 + k0, dA1);
        gload_lds16(pB0 + k0, dB0);
        gload_lds16(pB1 + k0, dB1);
        __syncthreads();
        bf16x8 af[4], bfr[4];
#pragma unroll
        for (int m = 0; m < 4; ++m)
            af[m] = *(const bf16x8*)&tA[(wr * 64 + m * 16 + llo) * 32 + lhi * 8];
#pragma unroll
        for (int n = 0; n < 4; ++n)
            bfr[n] = *(const bf16x8*)&tB[(wc * 64 + n * 16 + llo) * 32 + lhi * 8];
#pragma unroll
        for (int m = 0; m < 4; ++m)
#pragma unroll
            for (int n = 0; n < 4; ++n)
                acc[m][n] = __builtin_amdgcn_mfma_f32_16x16x32_bf16(af[m], bfr[n], acc[m][n], 0, 0, 0);
    }
#pragma unroll
    for (int m = 0; m < 4; ++m) {
        const int row0 = rowBase + wr * 64 + m * 16 + lhi * 4;
#pragma unroll
        for (int n = 0; n < 4; ++n) {
            const int col = colBase + wc * 64 + n * 16 + llo;
#pragma unroll
            for (int r2 = 0; r2 < 4; ++r2) {
                const size_t idx = (size_t)(row0 + r2) * N + col;
                if (OUT_BF16) Cb[idx] = (bf16_t)acc[m][n][r2];
                else          Cf[idx] = acc[m][n][r2];
            }
        }
    }
}

// ---------------- causal flash attention (r7-proven structure) ----------------
// grid: (SEQ/128, BATCH*HEADS), block 256 (4 waves x 32 q-rows), LPT qblk remap.
// THIS ROUND: softmax-B on the proven structure — exp2 domain, defer-max
// (lane-local check, P bounded by 2^8), deferred per-lane L partials (single
// epilogue reduce). Structure/staging/PV identical to r7.

__global__ __launch_bounds__(256) void flash_attn(const bf16_t* __restrict__ QKV,
                                                  bf16_t* __restrict__ Oout) {
    const int bh = blockIdx.y;
    const int qblk = (bh < 16) ? blockIdx.x : (15 - blockIdx.x);
    const int b = bh >> 4, h = bh & 15;
    const int tid = threadIdx.x;
    const int wave = tid >> 6, lane = tid & 63, lhi = lane >> 4, llo = lane & 15;
    const size_t rstride = 3 * DIM;
    const bf16_t* Qp = QKV + (size_t)b * SEQ * rstride + h * 64;
    const bf16_t* Kp = Qp + DIM;
    const bf16_t* Vp = Qp + 2 * DIM;

    __shared__ __align__(16) bf16_t Kt[2][KVB * 64];
    __shared__ __align__(16) bf16_t Vt[2][KVB * 64];
    __shared__ __align__(16) bf16_t Pt[4][32][72];

    const int qBase = qblk * QBLK;
    const int swz = 8 * (llo & 7);

    // Q fragments (registers for the whole kernel)
    bf16x8 qf[2][2];
#pragma unroll
    for (int m = 0; m < 2; ++m)
#pragma unroll
        for (int st = 0; st < 2; ++st)
            qf[m][st] = *(const bf16x8*)&Qp[(size_t)(qBase + wave * 32 + m * 16 + llo) * rstride + st * 32 + lhi * 8];

    // staging helpers
    const int krr = lane >> 3;
    const int ksrc = 8 * ((lane & 7) ^ krr);
    auto stageK = [&](int kt, int buf) {
#pragma unroll
        for (int p = 0; p < 2; ++p)
            gload_lds16(&Kp[(size_t)(kt * KVB + p * 32 + wave * 8 + krr) * rstride + ksrc],
                        &Kt[buf][p * 2048 + wave * 512]);
    };

    bf16x8 vreg0, vreg1;
    auto loadV = [&](int kt) {
        const bf16_t* g = &Vp[(size_t)(kt * KVB + lane) * rstride + wave * 16];
        vreg0 = *(const bf16x8*)g;
        vreg1 = *(const bf16x8*)(g + 8);
    };
    auto scatterV = [&](int buf) {
        const int c0 = wave * 16;
#pragma unroll
        for (int j = 0; j < 8; ++j) {
            Vt[buf][(c0 + j) * 64 + (lane ^ (8 * j))] = vreg0[j];
            Vt[buf][(c0 + 8 + j) * 64 + (lane ^ (8 * j))] = vreg1[j];
        }
    };

    f32x4 oacc[2][4] = {};
    float mrun[2][4], Lp[2][4];
#pragma unroll
    for (int m = 0; m < 2; ++m)
#pragma unroll
        for (int r = 0; r < 4; ++r) { mrun[m][r] = -1e30f; Lp[m][r] = 0.f; }

    const float SCL2 = 0.18033688f;   // 0.125 * log2(e): softmax in exp2 domain

    const int nt = 2 * qblk + 2;
    const int qmaxw = qBase + wave * 32 + 31;

    // prologue: stage tile 0
    stageK(0, 0);
    loadV(0);
    scatterV(0);
    __syncthreads();

    int cur = 0;
    for (int kt = 0; kt < nt; ++kt) {
        const bool havenext = (kt + 1) < nt;
        if (havenext) { stageK(kt + 1, cur ^ 1); loadV(kt + 1); }

        if (kt * KVB <= qmaxw) {
            // S = Q K^T
            f32x4 s[2][4] = {};
#pragma unroll
            for (int nb = 0; nb < 4; ++nb)
#pragma unroll
                for (int st = 0; st < 2; ++st) {
                    bf16x8 kf = *(const bf16x8*)&Kt[cur][(nb * 16 + llo) * 64 + ((st * 32 + lhi * 8) ^ swz)];
                    s[0][nb] = __builtin_amdgcn_mfma_f32_16x16x32_bf16(qf[0][st], kf, s[0][nb], 0, 0, 0);
                    s[1][nb] = __builtin_amdgcn_mfma_f32_16x16x32_bf16(qf[1][st], kf, s[1][nb], 0, 0, 0);
                }

            // softmax-B per m-subtile: exp2 domain, defer-max, per-lane L partial
#pragma unroll
            for (int m = 0; m < 2; ++m) {
                const int baseq = qBase + wave * 32 + m * 16;
                const int q0 = baseq + lhi * 4;
                float sv[4][4];
                float lmax[4] = {-1e30f, -1e30f, -1e30f, -1e30f};
                if (kt * KVB + 63 > baseq) {   // boundary tile: apply causal mask
#pragma unroll
                    for (int nb = 0; nb < 4; ++nb)
#pragma unroll
                        for (int r = 0; r < 4; ++r) {
                            float x = s[m][nb][r] * SCL2;
                            if (kt * KVB + nb * 16 + llo > q0 + r) x = -1e30f;
                            sv[nb][r] = x;
                            lmax[r] = fmaxf(lmax[r], x);
                        }
                } else {                        // interior tile: no mask math
#pragma unroll
                    for (int nb = 0; nb < 4; ++nb)
#pragma unroll
                        for (int r = 0; r < 4; ++r) {
                            float x = s[m][nb][r] * SCL2;
                            sv[nb][r] = x;
                            lmax[r] = fmaxf(lmax[r], x);
                        }
                }
                // defer-max: lane-local bound check; P <= 2^8 is safe in f32
                bool ok = true;
#pragma unroll
                for (int r = 0; r < 4; ++r) ok = ok && (lmax[r] <= mrun[m][r] + 8.0f);
                if (!__all(ok)) {
                    float mt[4] = {lmax[0], lmax[1], lmax[2], lmax[3]};
#pragma unroll
                    for (int off = 1; off < 16; off <<= 1)
#pragma unroll
                        for (int r = 0; r < 4; ++r) mt[r] = fmaxf(mt[r], __shfl_xor(mt[r], off, 64));
#pragma unroll
                    for (int r = 0; r < 4; ++r) {
                        float mn = fmaxf(mrun[m][r], mt[r]);
                        float alpha = exp2f(mrun[m][r] - mn);
                        mrun[m][r] = mn;
                        Lp[m][r] *= alpha;
#pragma unroll
                        for (int d = 0; d < 4; ++d) oacc[m][d][r] *= alpha;
                    }
                }
#pragma unroll
                for (int nb = 0; nb < 4; ++nb)
#pragma unroll
                    for (int r = 0; r < 4; ++r) {
                        float p = exp2f(sv[nb][r] - mrun[m][r]);
                        Lp[m][r] += p;
                        Pt[wave][m * 16 + lhi * 4 + r][nb * 16 + llo] = (bf16_t)p;
                    }
            }

            // O += P V
            bf16x8 pf[2][2];
#pragma unroll
            for (int m = 0; m < 2; ++m)
#pragma unroll
                for (int st = 0; st < 2; ++st)
                    pf[m][st] = *(const bf16x8*)&Pt[wave][m * 16 + llo][st * 32 + lhi * 8];
#pragma unroll
            for (int st = 0; st < 2; ++st)
#pragma unroll
                for (int d = 0; d < 4; ++d) {
                    bf16x8 vf = *(const bf16x8*)&Vt[cur][(d * 16 + llo) * 64 + ((st * 32 + lhi * 8) ^ swz)];
                    oacc[0][d] = __builtin_amdgcn_mfma_f32_16x16x32_bf16(pf[0][st], vf, oacc[0][d], 0, 0, 0);
                    oacc[1][d] = __builtin_amdgcn_mfma_f32_16x16x32_bf16(pf[1][st], vf, oacc[1][d], 0, 0, 0);
                }
        }

        if (havenext) scatterV(cur ^ 1);
        __syncthreads();
        cur ^= 1;
    }

    // epilogue: single 16-lane reduce of the per-lane L partials, then store
#pragma unroll
    for (int m = 0; m < 2; ++m) {
#pragma unroll
        for (int off = 1; off < 16; off <<= 1)
#pragma unroll
            for (int r = 0; r < 4; ++r) Lp[m][r] += __shfl_xor(Lp[m][r], off, 64);
#pragma unroll
        for (int r = 0; r < 4; ++r) {
            const int q = qBase + wave * 32 + m * 16 + lhi * 4 + r;
            const float inv = 1.0f / Lp[m][r];
            const size_t orow = (size_t)(b * SEQ + q) * DIM + h * 64;
#pragma unroll
            for (int d = 0; d < 4; ++d)
                Oout[orow + d * 16 + llo] = (bf16_t)(oacc[m][d][r] * inv);
        }
    }
}

// ---------------- launch ----------------

extern "C" void kernel_launch(void* const* d_in, const int* in_sizes, int n_in,
                              void* d_out, int out_size, void* d_ws, size_t ws_size,
                              hipStream_t stream) {
    (void)in_sizes; (void)n_in; (void)out_size; (void)ws_size;
    const float* batch   = (const float*)d_in[0];
    const float* W_qkv   = (const float*)d_in[1];
    const float* u_qkv   = (const float*)d_in[2];
    const float* sg_qkv  = (const float*)d_in[3];
    const float* W_proj  = (const float*)d_in[4];
    const float* u_proj  = (const float*)d_in[5];
    const float* sg_proj = (const float*)d_in[6];
    float* out = (float*)d_out;

    char* ws = (char*)d_ws;
    size_t off = 0;
    auto alloc = [&](size_t bytes) -> void* {
        void* p = ws + off;
        off = (off + bytes + 255) & ~(size_t)255;
        return p;
    };
    float* y_q    = (float*)alloc(1024 * 4);
    float* part_q = (float*)alloc(8 * 3072 * 4);
    float* sc_q   = (float*)alloc(4);
    float* y_p    = (float*)alloc(1024 * 4);
    float* part_p = (float*)alloc(8 * 1024 * 4);
    float* sc_p   = (float*)alloc(4);
    bf16_t* Xb   = (bf16_t*)alloc((size_t)MROWS * DIM * 2);
    bf16_t* Wtq  = (bf16_t*)alloc((size_t)3 * DIM * DIM * 2);
    bf16_t* Wtp  = (bf16_t*)alloc((size_t)DIM * DIM * 2);
    bf16_t* QKVb = (bf16_t*)alloc((size_t)MROWS * 3 * DIM * 2);
    bf16_t* AOb  = (bf16_t*)alloc((size_t)MROWS * DIM * 2);

    matvec_rows<<<1024, 256, 0, stream>>>(W_qkv, u_qkv, y_q, 3072);
    matvec_cols_part<<<dim3(12, 8), 256, 0, stream>>>(W_qkv, y_q, part_q, 3072);
    norm_scale<<<1, 1024, 0, stream>>>(y_q, 1024, part_q, 3072, sg_qkv, sc_q);

    matvec_rows<<<1024, 256, 0, stream>>>(W_proj, u_proj, y_p, 1024);
    matvec_cols_part<<<dim3(4, 8), 256, 0, stream>>>(W_proj, y_p, part_p, 1024);
    norm_scale<<<1, 1024, 0, stream>>>(y_p, 1024, part_p, 1024, sg_proj, sc_p);

    convert_x<<<(MROWS * DIM) / (256 * 4), 256, 0, stream>>>(batch, Xb, MROWS * DIM);
    convert_wt<<<dim3(3 * DIM / 32, DIM / 32), 256, 0, stream>>>(W_qkv, Wtq, sc_q, DIM, 3 * DIM);
    convert_wt<<<dim3(DIM / 32, DIM / 32), 256, 0, stream>>>(W_proj, Wtp, sc_p, DIM, DIM);

    gemm_bf16_128<1><<<dim3(3 * DIM / 128, MROWS / 128), 256, 0, stream>>>(
        Xb, Wtq, QKVb, nullptr, MROWS, 3 * DIM, DIM);

    flash_attn<<<dim3(SEQ / QBLK, BATCH * HEADS), 256, 0, stream>>>(QKVb, AOb);

    gemm_bf16_128<0><<<dim3(DIM / 128, MROWS / 128), 256, 0, stream>>>(
        AOb, Wtp, nullptr, out, MROWS, DIM, DIM);
}

// Round 9
// 183.507 us; speedup vs baseline: 3.9791x; 1.1227x over previous
//
#include <hip/hip_runtime.h>
#include <hip/hip_bf16.h>

#define DIM 1024
#define HEADS 16
#define BATCH 2
#define SEQ 2048
#define MROWS (BATCH*SEQ)   // 4096
#define KVB 64
#define QBLK 128

typedef __bf16 bf16_t;
typedef __bf16 bf16x8 __attribute__((ext_vector_type(8)));
typedef __bf16 bf16x4 __attribute__((ext_vector_type(4)));
typedef float  f32x4  __attribute__((ext_vector_type(4)));

__device__ inline float waveReduceSum(float v) {
#pragma unroll
    for (int off = 32; off > 0; off >>= 1) v += __shfl_down(v, off, 64);
    return v;
}

// async global->LDS 16B: LDS dest is wave-uniform base; HW writes base + lane*16.
__device__ inline void gload_lds16(const bf16_t* g, bf16_t* l) {
    __builtin_amdgcn_global_load_lds(
        (const __attribute__((address_space(1))) void*)g,
        (__attribute__((address_space(3))) void*)l,
        16, 0, 0);
}

// ---------------- power iteration (fused over both weights) ----------------
// scale = sp * ||W@u|| / ||W^T(W@u)||

__global__ __launch_bounds__(256) void matvec_rows2(const float* __restrict__ Wq,
                                                    const float* __restrict__ uq,
                                                    float* __restrict__ yq,
                                                    const float* __restrict__ Wp,
                                                    const float* __restrict__ up,
                                                    float* __restrict__ yp) {
    int row = blockIdx.x;
    const float* W; const float* x; float* y; int C;
    if (row < 1024) { W = Wq; x = uq; y = yq; C = 3072; }
    else            { W = Wp; x = up; y = yp; C = 1024; row -= 1024; }
    const float* Wr = W + (size_t)row * C;
    float acc = 0.f;
    for (int j = threadIdx.x; j < C; j += 256) acc += Wr[j] * x[j];
    __shared__ float red[4];
    float s = waveReduceSum(acc);
    if ((threadIdx.x & 63) == 0) red[threadIdx.x >> 6] = s;
    __syncthreads();
    if (threadIdx.x == 0) y[row] = red[0] + red[1] + red[2] + red[3];
}

__global__ __launch_bounds__(256) void matvec_cols_part2(const float* __restrict__ Wq,
                                                         const float* __restrict__ yq,
                                                         float* __restrict__ partq,
                                                         const float* __restrict__ Wp,
                                                         const float* __restrict__ yp,
                                                         float* __restrict__ partp) {
    const float* W; const float* y; float* part; int C; int j;
    if (blockIdx.x < 12) { W = Wq; y = yq; part = partq; C = 3072; j = blockIdx.x * 256 + threadIdx.x; }
    else                 { W = Wp; y = yp; part = partp; C = 1024; j = (blockIdx.x - 12) * 256 + threadIdx.x; }
    const int i0 = blockIdx.y * 128;
    float acc = 0.f;
#pragma unroll 4
    for (int i = i0; i < i0 + 128; ++i) acc += W[(size_t)i * C + j] * y[i];
    part[(size_t)blockIdx.y * C + j] = acc;
}

__global__ __launch_bounds__(1024) void norm_scale2(const float* __restrict__ yq,
                                                    const float* __restrict__ partq,
                                                    const float* __restrict__ spq,
                                                    float* __restrict__ scq,
                                                    const float* __restrict__ yp,
                                                    const float* __restrict__ partp,
                                                    const float* __restrict__ spp,
                                                    float* __restrict__ scp) {
    const float* y; const float* part; const float* sp; float* scale; int C;
    if (blockIdx.x == 0) { y = yq; part = partq; sp = spq; scale = scq; C = 3072; }
    else                 { y = yp; part = partp; sp = spp; scale = scp; C = 1024; }
    const int R = 1024;
    float accY = 0.f, accZ = 0.f;
    for (int i = threadIdx.x; i < R; i += 1024) { float t = y[i]; accY += t * t; }
    for (int j = threadIdx.x; j < C; j += 1024) {
        float z = 0.f;
#pragma unroll
        for (int p = 0; p < 8; ++p) z += part[(size_t)p * C + j];
        accZ += z * z;
    }
    __shared__ float redY[16], redZ[16];
    float sy = waveReduceSum(accY), sz = waveReduceSum(accZ);
    const int w = threadIdx.x >> 6;
    if ((threadIdx.x & 63) == 0) { redY[w] = sy; redZ[w] = sz; }
    __syncthreads();
    if (threadIdx.x == 0) {
        float SY = 0.f, SZ = 0.f;
#pragma unroll
        for (int i = 0; i < 16; ++i) { SY += redY[i]; SZ += redZ[i]; }
        scale[0] = sp[0] * sqrtf(SY) / sqrtf(SZ);
    }
}

// ---------------- conversions ----------------

__global__ __launch_bounds__(256) void convert_x(const float* __restrict__ X,
                                                 bf16_t* __restrict__ Xb, int n) {
    int i = (blockIdx.x * 256 + threadIdx.x) * 4;
    if (i + 3 < n) {
        float4 v = *(const float4*)(X + i);
        bf16x4 o;
        o[0] = (bf16_t)v.x; o[1] = (bf16_t)v.y; o[2] = (bf16_t)v.z; o[3] = (bf16_t)v.w;
        *(bf16x4*)(Xb + i) = o;
    }
}

// both weight transposes in one launch: bx<96 -> qkv tile, else proj tile
__global__ __launch_bounds__(256) void convert_wt2(const float* __restrict__ Wq,
                                                   bf16_t* __restrict__ Wtq,
                                                   const float* __restrict__ scq,
                                                   const float* __restrict__ Wp,
                                                   bf16_t* __restrict__ Wtp,
                                                   const float* __restrict__ scp) {
    __shared__ float t[32][33];
    const float* W; bf16_t* Wt; const float* scalep; int R, C, bxb;
    if (blockIdx.x < 96) { W = Wq; Wt = Wtq; scalep = scq; R = 1024; C = 3072; bxb = blockIdx.x; }
    else                 { W = Wp; Wt = Wtp; scalep = scp; R = 1024; C = 1024; bxb = blockIdx.x - 96; }
    const float s = *scalep;
    const int bx = bxb * 32;
    const int by = blockIdx.y * 32;
    const int tx = threadIdx.x & 31;
    const int ty = threadIdx.x >> 5;
#pragma unroll
    for (int j = ty; j < 32; j += 8)
        t[j][tx] = W[(size_t)(by + j) * C + bx + tx];
    __syncthreads();
#pragma unroll
    for (int j = ty; j < 32; j += 8)
        Wt[(size_t)(bx + j) * R + by + tx] = (bf16_t)(t[tx][j] * s);
}

// ---------------- bf16 MFMA GEMM (m97 structure + XCD-bijective swizzle) -----

template <int OUT_BF16>
__global__ __launch_bounds__(256) void gemm_bf16_128(const bf16_t* __restrict__ A,
                                                     const bf16_t* __restrict__ Bt,
                                                     bf16_t* __restrict__ Cb,
                                                     float* __restrict__ Cf,
                                                     int M, int N, int K) {
    __shared__ __align__(16) bf16_t tA[128 * 32];
    __shared__ __align__(16) bf16_t tB[128 * 32];
    const int tid = threadIdx.x;
    const int wave = tid >> 6, lane = tid & 63, lhi = lane >> 4, llo = lane & 15;
    const int wr = wave >> 1, wc = wave & 1;

    // XCD swizzle (bijective: grid size % 8 == 0): dispatch id o goes to XCD
    // o%8; logical tile (o%8)*q + o/8 gives each XCD a contiguous tile chunk.
    const int nwg = gridDim.x * gridDim.y;
    const int q = nwg >> 3;
    const int bid = blockIdx.y * gridDim.x + blockIdx.x;
    const int wgid = (bid & 7) * q + (bid >> 3);
    const int bx = wgid % gridDim.x;
    const int by = wgid / gridDim.x;

    const int rowBase = by * 128, colBase = bx * 128;

    const int srow = wave * 16 + (lane >> 2);
    const int scol = (lane & 3) * 8;
    const bf16_t* pA0 = &A[(size_t)(rowBase + srow) * K + scol];
    const bf16_t* pA1 = &A[(size_t)(rowBase + 64 + srow) * K + scol];
    const bf16_t* pB0 = &Bt[(size_t)(colBase + srow) * K + scol];
    const bf16_t* pB1 = &Bt[(size_t)(colBase + 64 + srow) * K + scol];
    bf16_t* dA0 = tA + wave * 512;
    bf16_t* dA1 = tA + 2048 + wave * 512;
    bf16_t* dB0 = tB + wave * 512;
    bf16_t* dB1 = tB + 2048 + wave * 512;

    f32x4 acc[4][4] = {};
    for (int k0 = 0; k0 < K; k0 += 32) {
        __syncthreads();
        gload_lds16(pA0 + k0, dA0);
        gload_lds16(pA1 + k0, dA1);
        gload_lds16(pB0 + k0, dB0);
        gload_lds16(pB1 + k0, dB1);
        __syncthreads();
        bf16x8 af[4], bfr[4];
#pragma unroll
        for (int m = 0; m < 4; ++m)
            af[m] = *(const bf16x8*)&tA[(wr * 64 + m * 16 + llo) * 32 + lhi * 8];
#pragma unroll
        for (int n = 0; n < 4; ++n)
            bfr[n] = *(const bf16x8*)&tB[(wc * 64 + n * 16 + llo) * 32 + lhi * 8];
#pragma unroll
        for (int m = 0; m < 4; ++m)
#pragma unroll
            for (int n = 0; n < 4; ++n)
                acc[m][n] = __builtin_amdgcn_mfma_f32_16x16x32_bf16(af[m], bfr[n], acc[m][n], 0, 0, 0);
    }
#pragma unroll
    for (int m = 0; m < 4; ++m) {
        const int row0 = rowBase + wr * 64 + m * 16 + lhi * 4;
#pragma unroll
        for (int n = 0; n < 4; ++n) {
            const int col = colBase + wc * 64 + n * 16 + llo;
#pragma unroll
            for (int r2 = 0; r2 < 4; ++r2) {
                const size_t idx = (size_t)(row0 + r2) * N + col;
                if (OUT_BF16) Cb[idx] = (bf16_t)acc[m][n][r2];
                else          Cf[idx] = acc[m][n][r2];
            }
        }
    }
}

// ---------------- causal flash attention (r8-proven + T5 setprio) ------------
// grid: (SEQ/128, BATCH*HEADS), block 256 (4 waves x 32 q-rows), LPT qblk remap,
// softmax-B (exp2, defer-max, deferred L partials).

__global__ __launch_bounds__(256) void flash_attn(const bf16_t* __restrict__ QKV,
                                                  bf16_t* __restrict__ Oout) {
    const int bh = blockIdx.y;
    const int qblk = (bh < 16) ? blockIdx.x : (15 - blockIdx.x);
    const int b = bh >> 4, h = bh & 15;
    const int tid = threadIdx.x;
    const int wave = tid >> 6, lane = tid & 63, lhi = lane >> 4, llo = lane & 15;
    const size_t rstride = 3 * DIM;
    const bf16_t* Qp = QKV + (size_t)b * SEQ * rstride + h * 64;
    const bf16_t* Kp = Qp + DIM;
    const bf16_t* Vp = Qp + 2 * DIM;

    __shared__ __align__(16) bf16_t Kt[2][KVB * 64];
    __shared__ __align__(16) bf16_t Vt[2][KVB * 64];
    __shared__ __align__(16) bf16_t Pt[4][32][72];

    const int qBase = qblk * QBLK;
    const int swz = 8 * (llo & 7);

    bf16x8 qf[2][2];
#pragma unroll
    for (int m = 0; m < 2; ++m)
#pragma unroll
        for (int st = 0; st < 2; ++st)
            qf[m][st] = *(const bf16x8*)&Qp[(size_t)(qBase + wave * 32 + m * 16 + llo) * rstride + st * 32 + lhi * 8];

    const int krr = lane >> 3;
    const int ksrc = 8 * ((lane & 7) ^ krr);
    auto stageK = [&](int kt, int buf) {
#pragma unroll
        for (int p = 0; p < 2; ++p)
            gload_lds16(&Kp[(size_t)(kt * KVB + p * 32 + wave * 8 + krr) * rstride + ksrc],
                        &Kt[buf][p * 2048 + wave * 512]);
    };

    bf16x8 vreg0, vreg1;
    auto loadV = [&](int kt) {
        const bf16_t* g = &Vp[(size_t)(kt * KVB + lane) * rstride + wave * 16];
        vreg0 = *(const bf16x8*)g;
        vreg1 = *(const bf16x8*)(g + 8);
    };
    auto scatterV = [&](int buf) {
        const int c0 = wave * 16;
#pragma unroll
        for (int j = 0; j < 8; ++j) {
            Vt[buf][(c0 + j) * 64 + (lane ^ (8 * j))] = vreg0[j];
            Vt[buf][(c0 + 8 + j) * 64 + (lane ^ (8 * j))] = vreg1[j];
        }
    };

    f32x4 oacc[2][4] = {};
    float mrun[2][4], Lp[2][4];
#pragma unroll
    for (int m = 0; m < 2; ++m)
#pragma unroll
        for (int r = 0; r < 4; ++r) { mrun[m][r] = -1e30f; Lp[m][r] = 0.f; }

    const float SCL2 = 0.18033688f;   // 0.125 * log2(e)

    const int nt = 2 * qblk + 2;
    const int qmaxw = qBase + wave * 32 + 31;

    stageK(0, 0);
    loadV(0);
    scatterV(0);
    __syncthreads();

    int cur = 0;
    for (int kt = 0; kt < nt; ++kt) {
        const bool havenext = (kt + 1) < nt;
        if (havenext) { stageK(kt + 1, cur ^ 1); loadV(kt + 1); }

        if (kt * KVB <= qmaxw) {
            // S = Q K^T (T5: boost wave priority through the MFMA cluster)
            f32x4 s[2][4] = {};
            __builtin_amdgcn_s_setprio(1);
#pragma unroll
            for (int nb = 0; nb < 4; ++nb)
#pragma unroll
                for (int st = 0; st < 2; ++st) {
                    bf16x8 kf = *(const bf16x8*)&Kt[cur][(nb * 16 + llo) * 64 + ((st * 32 + lhi * 8) ^ swz)];
                    s[0][nb] = __builtin_amdgcn_mfma_f32_16x16x32_bf16(qf[0][st], kf, s[0][nb], 0, 0, 0);
                    s[1][nb] = __builtin_amdgcn_mfma_f32_16x16x32_bf16(qf[1][st], kf, s[1][nb], 0, 0, 0);
                }
            __builtin_amdgcn_s_setprio(0);

            // softmax-B per m-subtile
#pragma unroll
            for (int m = 0; m < 2; ++m) {
                const int baseq = qBase + wave * 32 + m * 16;
                const int q0 = baseq + lhi * 4;
                float sv[4][4];
                float lmax[4] = {-1e30f, -1e30f, -1e30f, -1e30f};
                if (kt * KVB + 63 > baseq) {
#pragma unroll
                    for (int nb = 0; nb < 4; ++nb)
#pragma unroll
                        for (int r = 0; r < 4; ++r) {
                            float x = s[m][nb][r] * SCL2;
                            if (kt * KVB + nb * 16 + llo > q0 + r) x = -1e30f;
                            sv[nb][r] = x;
                            lmax[r] = fmaxf(lmax[r], x);
                        }
                } else {
#pragma unroll
                    for (int nb = 0; nb < 4; ++nb)
#pragma unroll
                        for (int r = 0; r < 4; ++r) {
                            float x = s[m][nb][r] * SCL2;
                            sv[nb][r] = x;
                            lmax[r] = fmaxf(lmax[r], x);
                        }
                }
                bool ok = true;
#pragma unroll
                for (int r = 0; r < 4; ++r) ok = ok && (lmax[r] <= mrun[m][r] + 8.0f);
                if (!__all(ok)) {
                    float mt[4] = {lmax[0], lmax[1], lmax[2], lmax[3]};
#pragma unroll
                    for (int off = 1; off < 16; off <<= 1)
#pragma unroll
                        for (int r = 0; r < 4; ++r) mt[r] = fmaxf(mt[r], __shfl_xor(mt[r], off, 64));
#pragma unroll
                    for (int r = 0; r < 4; ++r) {
                        float mn = fmaxf(mrun[m][r], mt[r]);
                        float alpha = exp2f(mrun[m][r] - mn);
                        mrun[m][r] = mn;
                        Lp[m][r] *= alpha;
#pragma unroll
                        for (int d = 0; d < 4; ++d) oacc[m][d][r] *= alpha;
                    }
                }
#pragma unroll
                for (int nb = 0; nb < 4; ++nb)
#pragma unroll
                    for (int r = 0; r < 4; ++r) {
                        float p = exp2f(sv[nb][r] - mrun[m][r]);
                        Lp[m][r] += p;
                        Pt[wave][m * 16 + lhi * 4 + r][nb * 16 + llo] = (bf16_t)p;
                    }
            }

            // O += P V
            bf16x8 pf[2][2];
#pragma unroll
            for (int m = 0; m < 2; ++m)
#pragma unroll
                for (int st = 0; st < 2; ++st)
                    pf[m][st] = *(const bf16x8*)&Pt[wave][m * 16 + llo][st * 32 + lhi * 8];
            __builtin_amdgcn_s_setprio(1);
#pragma unroll
            for (int st = 0; st < 2; ++st)
#pragma unroll
                for (int d = 0; d < 4; ++d) {
                    bf16x8 vf = *(const bf16x8*)&Vt[cur][(d * 16 + llo) * 64 + ((st * 32 + lhi * 8) ^ swz)];
                    oacc[0][d] = __builtin_amdgcn_mfma_f32_16x16x32_bf16(pf[0][st], vf, oacc[0][d], 0, 0, 0);
                    oacc[1][d] = __builtin_amdgcn_mfma_f32_16x16x32_bf16(pf[1][st], vf, oacc[1][d], 0, 0, 0);
                }
            __builtin_amdgcn_s_setprio(0);
        }

        if (havenext) scatterV(cur ^ 1);
        __syncthreads();
        cur ^= 1;
    }

    // epilogue: single 16-lane reduce of per-lane L partials, then store
#pragma unroll
    for (int m = 0; m < 2; ++m) {
#pragma unroll
        for (int off = 1; off < 16; off <<= 1)
#pragma unroll
            for (int r = 0; r < 4; ++r) Lp[m][r] += __shfl_xor(Lp[m][r], off, 64);
#pragma unroll
        for (int r = 0; r < 4; ++r) {
            const int q = qBase + wave * 32 + m * 16 + lhi * 4 + r;
            const float inv = 1.0f / Lp[m][r];
            const size_t orow = (size_t)(b * SEQ + q) * DIM + h * 64;
#pragma unroll
            for (int d = 0; d < 4; ++d)
                Oout[orow + d * 16 + llo] = (bf16_t)(oacc[m][d][r] * inv);
        }
    }
}

// ---------------- launch ----------------

extern "C" void kernel_launch(void* const* d_in, const int* in_sizes, int n_in,
                              void* d_out, int out_size, void* d_ws, size_t ws_size,
                              hipStream_t stream) {
    (void)in_sizes; (void)n_in; (void)out_size; (void)ws_size;
    const float* batch   = (const float*)d_in[0];
    const float* W_qkv   = (const float*)d_in[1];
    const float* u_qkv   = (const float*)d_in[2];
    const float* sg_qkv  = (const float*)d_in[3];
    const float* W_proj  = (const float*)d_in[4];
    const float* u_proj  = (const float*)d_in[5];
    const float* sg_proj = (const float*)d_in[6];
    float* out = (float*)d_out;

    char* ws = (char*)d_ws;
    size_t off = 0;
    auto alloc = [&](size_t bytes) -> void* {
        void* p = ws + off;
        off = (off + bytes + 255) & ~(size_t)255;
        return p;
    };
    float* y_q    = (float*)alloc(1024 * 4);
    float* part_q = (float*)alloc(8 * 3072 * 4);
    float* sc_q   = (float*)alloc(4);
    float* y_p    = (float*)alloc(1024 * 4);
    float* part_p = (float*)alloc(8 * 1024 * 4);
    float* sc_p   = (float*)alloc(4);
    bf16_t* Xb   = (bf16_t*)alloc((size_t)MROWS * DIM * 2);
    bf16_t* Wtq  = (bf16_t*)alloc((size_t)3 * DIM * DIM * 2);
    bf16_t* Wtp  = (bf16_t*)alloc((size_t)DIM * DIM * 2);
    bf16_t* QKVb = (bf16_t*)alloc((size_t)MROWS * 3 * DIM * 2);
    bf16_t* AOb  = (bf16_t*)alloc((size_t)MROWS * DIM * 2);

    // power iteration, both weights fused per stage
    matvec_rows2<<<2048, 256, 0, stream>>>(W_qkv, u_qkv, y_q, W_proj, u_proj, y_p);
    matvec_cols_part2<<<dim3(16, 8), 256, 0, stream>>>(W_qkv, y_q, part_q, W_proj, y_p, part_p);
    norm_scale2<<<2, 1024, 0, stream>>>(y_q, part_q, sg_qkv, sc_q, y_p, part_p, sg_proj, sc_p);

    // conversions
    convert_x<<<(MROWS * DIM) / (256 * 4), 256, 0, stream>>>(batch, Xb, MROWS * DIM);
    convert_wt2<<<dim3(128, 32), 256, 0, stream>>>(W_qkv, Wtq, sc_q, W_proj, Wtp, sc_p);

    // QKV = Xb @ (s*W_qkv)
    gemm_bf16_128<1><<<dim3(3 * DIM / 128, MROWS / 128), 256, 0, stream>>>(
        Xb, Wtq, QKVb, nullptr, MROWS, 3 * DIM, DIM);

    // attention
    flash_attn<<<dim3(SEQ / QBLK, BATCH * HEADS), 256, 0, stream>>>(QKVb, AOb);

    // out = AOb @ (s*W_proj)
    gemm_bf16_128<0><<<dim3(DIM / 128, MROWS / 128), 256, 0, stream>>>(
        AOb, Wtp, nullptr, out, MROWS, DIM, DIM);
}